// Round 18
// baseline (906.248 us; speedup 1.0000x reference)
//
#include <hip/hip_runtime.h>

// ---------------- problem constants ----------------
#define B_    2
#define S_    2048
#define HID_  3584
#define NH_   16
#define NKV_  8
#define HD_   256
#define DQ_   (NH_ * HD_)    // 4096
#define DKV_  (NKV_ * HD_)   // 2048

static constexpr float SCALE_ = 0.0625f;   // 256^-0.5

typedef __bf16 bf16_t;
typedef __bf16 bf16x8 __attribute__((ext_vector_type(8)));
typedef __bf16 bf16x4 __attribute__((ext_vector_type(4)));
typedef float  f32x4  __attribute__((ext_vector_type(4)));

// ---------------- f32 -> bf16 convert ----------------
__global__ __launch_bounds__(256) void cvt_kernel(const float* __restrict__ in,
                                                  bf16_t* __restrict__ out, int n4) {
  int i = blockIdx.x * 256 + threadIdx.x;
  if (i < n4) {
    float4 v = ((const float4*)in)[i];
    bf16x4 o;
    o[0] = (bf16_t)v.x; o[1] = (bf16_t)v.y; o[2] = (bf16_t)v.z; o[3] = (bf16_t)v.w;
    ((bf16x4*)out)[i] = o;
  }
}

// ---------------- async global->LDS, 16B per lane ----------------
__device__ inline void gload_lds16(const bf16_t* g, bf16_t* l) {
  __builtin_amdgcn_global_load_lds(
      (const __attribute__((address_space(1))) void*)g,
      (__attribute__((address_space(3))) void*)l, 16, 0, 0);
}

// ---------------- 256x256 8-wave pipelined GEMM: C[m][n] = sum_k A[m][k]*Bt[n][k] ----------------
// 512 thr = 2(M)x4(N) waves, each 128x64 C (acc[8][4]). BK=64, double-buffered 128KB LDS.
// 1-ahead prefetch, ALL 8 sites issued right after the barrier; single barrier per K-tile.
// Swizzle: source col unit ^= row&7 at staging; same XOR on ds_read (involution).
// MODE 0: OUT f32 row-major [M][N]                         (o-proj -> d_out)
// MODE 4: merged QKV: col<DQ -> Q relayout (outv);
//         col<DQ+DKV -> K relayout (out2v); else V transpose (out3v)
template<int MODE>
__global__ __launch_bounds__(512, 1) void gemm256(const bf16_t* __restrict__ A,
                                                  const bf16_t* __restrict__ Bt,
                                                  void* __restrict__ outv,
                                                  void* __restrict__ out2v,
                                                  void* __restrict__ out3v,
                                                  int M, int N, int K) {
  __shared__ __align__(16) bf16_t As[2][256 * 64];   // 64 KB
  __shared__ __align__(16) bf16_t Bs[2][256 * 64];   // 64 KB
  const int t = threadIdx.x;
  const int lane = t & 63, wv = t >> 6;
  const int wr = wv >> 2, wc = wv & 3;
  const int lr = lane & 15, lg = lane >> 4;
  const size_t m0 = (size_t)blockIdx.y * 256, n0 = (size_t)blockIdx.x * 256;

  const int srow = wv * 8 + (lane >> 3);
  const int scol = ((lane & 7) ^ ((lane >> 3) & 7)) * 8;   // pre-swizzled source col
  const bf16_t* ga = A  + (m0 + srow) * (size_t)K + scol;
  const bf16_t* gb = Bt + (n0 + srow) * (size_t)K + scol;
  const int ldso = wv * 512;   // wave-uniform LDS offset (elems)

#define SITEA(rb, kc, pp) gload_lds16(ga + (size_t)(rb) * K + (kc), &As[pp][(rb) * 64 + ldso])
#define SITEB(rb, kc, pp) gload_lds16(gb + (size_t)(rb) * K + (kc), &Bs[pp][(rb) * 64 + ldso])

  const int NT = K >> 6;
  f32x4 acc[8][4] = {};
  bf16x8 af[4][2], bfr[2][2];

  const int swz0 = ((0 + lg) ^ (lr & 7)) * 8;
  const int swz1 = ((4 + lg) ^ (lr & 7)) * 8;
  const int aRB = (wr * 128 + lr) * 64;
  const int bRB = (wc * 64 + lr) * 64;

  SITEA(0, 0, 0); SITEA(64, 0, 0); SITEA(128, 0, 0); SITEA(192, 0, 0);
  SITEB(0, 0, 0); SITEB(64, 0, 0); SITEB(128, 0, 0); SITEB(192, 0, 0);

  for (int kt = 0; kt < NT; ++kt) {
    const int p = kt & 1, q = p ^ 1;
    __syncthreads();              // vmcnt drain: buf[p] staged & visible
    if (kt + 1 < NT) {            // issue ALL next-tile loads up front
      const int kn = (kt + 1) << 6;
      SITEA(0, kn, q); SITEA(64, kn, q); SITEA(128, kn, q); SITEA(192, kn, q);
      SITEB(0, kn, q); SITEB(64, kn, q); SITEB(128, kn, q); SITEB(192, kn, q);
    }

    // phase 0: i0-3 x j0-1
#pragma unroll
    for (int i = 0; i < 4; ++i) {
      af[i][0] = *(const bf16x8*)&As[p][aRB + i * 1024 + swz0];
      af[i][1] = *(const bf16x8*)&As[p][aRB + i * 1024 + swz1];
    }
#pragma unroll
    for (int j = 0; j < 2; ++j) {
      bfr[j][0] = *(const bf16x8*)&Bs[p][bRB + j * 1024 + swz0];
      bfr[j][1] = *(const bf16x8*)&Bs[p][bRB + j * 1024 + swz1];
    }
#pragma unroll
    for (int i = 0; i < 4; ++i)
#pragma unroll
      for (int j = 0; j < 2; ++j) {
        acc[i][j] = __builtin_amdgcn_mfma_f32_16x16x32_bf16(af[i][0], bfr[j][0], acc[i][j], 0, 0, 0);
        acc[i][j] = __builtin_amdgcn_mfma_f32_16x16x32_bf16(af[i][1], bfr[j][1], acc[i][j], 0, 0, 0);
      }

    // phase 1: i4-7 x j0-1
#pragma unroll
    for (int i = 0; i < 4; ++i) {
      af[i][0] = *(const bf16x8*)&As[p][aRB + (i + 4) * 1024 + swz0];
      af[i][1] = *(const bf16x8*)&As[p][aRB + (i + 4) * 1024 + swz1];
    }
#pragma unroll
    for (int i = 0; i < 4; ++i)
#pragma unroll
      for (int j = 0; j < 2; ++j) {
        acc[i + 4][j] = __builtin_amdgcn_mfma_f32_16x16x32_bf16(af[i][0], bfr[j][0], acc[i + 4][j], 0, 0, 0);
        acc[i + 4][j] = __builtin_amdgcn_mfma_f32_16x16x32_bf16(af[i][1], bfr[j][1], acc[i + 4][j], 0, 0, 0);
      }

    // phase 2: i4-7 x j2-3
#pragma unroll
    for (int j = 0; j < 2; ++j) {
      bfr[j][0] = *(const bf16x8*)&Bs[p][bRB + (j + 2) * 1024 + swz0];
      bfr[j][1] = *(const bf16x8*)&Bs[p][bRB + (j + 2) * 1024 + swz1];
    }
#pragma unroll
    for (int i = 0; i < 4; ++i)
#pragma unroll
      for (int j = 0; j < 2; ++j) {
        acc[i + 4][j + 2] = __builtin_amdgcn_mfma_f32_16x16x32_bf16(af[i][0], bfr[j][0], acc[i + 4][j + 2], 0, 0, 0);
        acc[i + 4][j + 2] = __builtin_amdgcn_mfma_f32_16x16x32_bf16(af[i][1], bfr[j][1], acc[i + 4][j + 2], 0, 0, 0);
      }

    // phase 3: i0-3 x j2-3
#pragma unroll
    for (int i = 0; i < 4; ++i) {
      af[i][0] = *(const bf16x8*)&As[p][aRB + i * 1024 + swz0];
      af[i][1] = *(const bf16x8*)&As[p][aRB + i * 1024 + swz1];
    }
#pragma unroll
    for (int i = 0; i < 4; ++i)
#pragma unroll
      for (int j = 0; j < 2; ++j) {
        acc[i][j + 2] = __builtin_amdgcn_mfma_f32_16x16x32_bf16(af[i][0], bfr[j][0], acc[i][j + 2], 0, 0, 0);
        acc[i][j + 2] = __builtin_amdgcn_mfma_f32_16x16x32_bf16(af[i][1], bfr[j][1], acc[i][j + 2], 0, 0, 0);
      }
  }
#undef SITEA
#undef SITEB

#pragma unroll
  for (int i = 0; i < 8; ++i)
#pragma unroll
    for (int j = 0; j < 4; ++j) {
      const int row0 = (int)m0 + wr * 128 + i * 16 + lg * 4;
      const int col  = (int)n0 + wc * 64 + j * 16 + lr;
#pragma unroll
      for (int r = 0; r < 4; ++r) {
        const int row = row0 + r;
        if (MODE == 0) {
          ((float*)outv)[(size_t)row * N + col] = acc[i][j][r];
        } else {  // MODE 4: merged QKV epilogue
          const bf16_t val = (bf16_t)acc[i][j][r];
          const int b = row >> 11, s = row & (S_ - 1);
          if (col < DQ_) {
            const int h = col >> 8, hd = col & (HD_ - 1);
            ((bf16_t*)outv)[((size_t)(b * NH_ + h) * S_ + s) * HD_ + hd] = val;
          } else if (col < DQ_ + DKV_) {
            const int c2 = col - DQ_;
            const int h = c2 >> 8, hd = c2 & (HD_ - 1);
            ((bf16_t*)out2v)[((size_t)(b * NKV_ + h) * S_ + s) * HD_ + hd] = val;
          } else {
            const int c2 = col - DQ_ - DKV_;
            const int h = c2 >> 8, hd = c2 & (HD_ - 1);
            ((bf16_t*)out3v)[((size_t)(b * NKV_ + h) * HD_ + hd) * S_ + s] = val;
          }
        }
      }
    }
}

// ---------------- merged RMSNorm + RoPE (Q then K segments), in place ----------------
// Always writes per-row |x|^2 (pre-bf16-rounding; RoPE preserves norm).
__global__ __launch_bounds__(256) void normrope2_kernel(bf16_t* __restrict__ qb,
                                                        bf16_t* __restrict__ kb,
                                                        const float* __restrict__ qw,
                                                        const float* __restrict__ kw,
                                                        const float* __restrict__ cosb,
                                                        const float* __restrict__ sinb,
                                                        float* __restrict__ qnorm,
                                                        float* __restrict__ knorm) {
  int gid = blockIdx.x * 4 + (threadIdx.x >> 6);
  const int lane = threadIdx.x & 63;
  bf16_t* x; const float* w; float* rn; int lognh;
  if (gid < B_ * S_ * NH_) { x = qb; w = qw; rn = qnorm; lognh = 4; }
  else { gid -= B_ * S_ * NH_; x = kb; w = kw; rn = knorm; lognh = 3; }
  const int nh = 1 << lognh;
  const int h  = gid & (nh - 1);
  const int bs = gid >> lognh;                 // b*S + s
  const int b  = bs >> 11, s = bs & (S_ - 1);
  const int rowi = (b * nh + h) * S_ + s;

  bf16_t* ptr = x + (size_t)rowi * HD_ + lane * 4;
  bf16x4 xv = *(const bf16x4*)ptr;
  float v0 = (float)xv[0], v1 = (float)xv[1], v2 = (float)xv[2], v3 = (float)xv[3];
  float ss = v0 * v0 + v1 * v1 + v2 * v2 + v3 * v3;
#pragma unroll
  for (int off = 1; off < 64; off <<= 1) ss += __shfl_xor(ss, off);
  float r = rsqrtf(ss * (1.0f / HD_) + 1e-6f);

  float4 wv = *(const float4*)(w + lane * 4);
  float x0 = v0 * r * (1.0f + wv.x);
  float x1 = v1 * r * (1.0f + wv.y);
  float x2 = v2 * r * (1.0f + wv.z);
  float x3 = v3 * r * (1.0f + wv.w);

  float s2 = x0 * x0 + x1 * x1 + x2 * x2 + x3 * x3;
#pragma unroll
  for (int off = 1; off < 64; off <<= 1) s2 += __shfl_xor(s2, off);
  if (lane == 0) rn[rowi] = s2;

  float p0 = __shfl_xor(x0, 32);
  float p1 = __shfl_xor(x1, 32);
  float p2 = __shfl_xor(x2, 32);
  float p3 = __shfl_xor(x3, 32);
  float sgn = (lane < 32) ? -1.0f : 1.0f;

  float4 c  = *(const float4*)(cosb + (size_t)bs * HD_ + lane * 4);
  float4 sn = *(const float4*)(sinb + (size_t)bs * HD_ + lane * 4);
  bf16x4 o;
  o[0] = (bf16_t)(x0 * c.x + sgn * p0 * sn.x);
  o[1] = (bf16_t)(x1 * c.y + sgn * p1 * sn.y);
  o[2] = (bf16_t)(x2 * c.z + sgn * p2 * sn.z);
  o[3] = (bf16_t)(x3 * c.w + sgn * p3 * sn.w);
  *(bf16x4*)ptr = o;
}

// ---------------- per-(b,kv-head) max of knorm ----------------
__global__ __launch_bounds__(256) void kmax_reduce_kernel(const float* __restrict__ knorm,
                                                          float* __restrict__ km) {
  __shared__ float red[4];
  const int t = threadIdx.x;
  const float* src = knorm + (size_t)blockIdx.x * S_;
  float m = 0.0f;
  for (int i = t; i < S_; i += 256) m = fmaxf(m, src[i]);
#pragma unroll
  for (int off = 1; off < 64; off <<= 1) m = fmaxf(m, __shfl_xor(m, off));
  if ((t & 63) == 0) red[t >> 6] = m;
  __syncthreads();
  if (t == 0) km[blockIdx.x] = fmaxf(fmaxf(red[0], red[1]), fmaxf(red[2], red[3]));
}

// ---------------- single-pass flash attention (XCD-pinned, LPT, T14 reg-prefetch) ----------------
// mb now read from qnorm (hoisted to normrope); no in-kernel row-norm reduction.
__global__ __launch_bounds__(256) void attn1p_kernel(const bf16_t* __restrict__ qb,
                                                     const bf16_t* __restrict__ kb,
                                                     const bf16_t* __restrict__ vt,
                                                     const float* __restrict__ qnorm,
                                                     const float* __restrict__ kmaxbuf,
                                                     bf16_t* __restrict__ pt,
                                                     float* __restrict__ linv,
                                                     bf16_t* __restrict__ ctx) {
  __shared__ __align__(16) bf16_t Ks[32][264];      // +8 pad
  __shared__ __align__(16) bf16_t Vs[256][36];      // d-major, +4 pad
  __shared__ __align__(16) bf16_t p_lds[4][16][36];

  const int t = threadIdx.x, w = t >> 6, lane = t & 63;
  const int lr = lane & 15, lg = lane >> 4, rloc = lg * 4;

  // XCD-pinned decode (wgid%8 = XCD round-robin); LPT: heavy q-buckets first
  const int wgid = blockIdx.x;
  const int g    = ((wgid >> 9) << 3) | (wgid & 7);   // (b*NKV + kvh) group, 0..15
  const int idx  = (wgid >> 3) & 63;
  const int b    = g >> 3, kvh = g & 7;
  const int h    = kvh * 2 + (idx >> 5);
  const int qbucket = 31 - (idx & 31);                // descending: longest first
  const int bh   = b * NH_ + h;
  const int q0b  = qbucket * 64;
  const int q0   = q0b + w * 16;

  const bf16_t* qptr = qb + ((size_t)bh * S_ + q0 + lr) * HD_ + lg * 8;
  bf16x8 qf[8];
#pragma unroll
  for (int c = 0; c < 8; ++c) qf[c] = *(const bf16x8*)(qptr + c * 32);

  const float kmax2 = kmaxbuf[b * NKV_ + kvh];
  float mb[4];
#pragma unroll
  for (int r = 0; r < 4; ++r)
    mb[r] = SCALE_ * sqrtf(qnorm[(size_t)bh * S_ + q0 + rloc + r] * kmax2) + 1.0f;

  float l[4] = {0.f, 0.f, 0.f, 0.f};
  f32x4 oacc[16] = {};
  const int nkt = (q0b + 64) >> 5;
  bf16_t* prow_g = pt + ((size_t)bh * S_ + q0) * S_;
  const bf16_t* kgb = kb + (size_t)(b * NKV_ + kvh) * S_ * HD_;
  const bf16_t* vgb = vt + (size_t)(b * NKV_ + kvh) * HD_ * S_;

  const int s_st = t >> 3, c_st = (t & 7) * 32;   // K staging: row s_st, 4x8 cols
  const int vd   = t >> 3, vc   = (t & 7) * 4;    // V staging: rows vd+32i, 4 cols
  const int prow = lane >> 2, pcol = (lane & 3) * 8;  // p-tilde store geometry

  // ---- prefetch tile 0 into registers ----
  bf16x8 kreg0, kreg1, kreg2, kreg3;
  bf16x4 vreg[8];
  {
    const bf16_t* src = kgb + (size_t)s_st * HD_ + c_st;
    kreg0 = *(const bf16x8*)(src);
    kreg1 = *(const bf16x8*)(src + 8);
    kreg2 = *(const bf16x8*)(src + 16);
    kreg3 = *(const bf16x8*)(src + 24);
#pragma unroll
    for (int i = 0; i < 8; ++i)
      vreg[i] = *(const bf16x4*)(vgb + (size_t)(vd + i * 32) * S_ + vc);
  }

  for (int kt = 0; kt < nkt; ++kt) {
    const int colb = kt * 32;
    __syncthreads();   // previous tile's LDS reads complete
    *(bf16x8*)&Ks[s_st][c_st]      = kreg0;
    *(bf16x8*)&Ks[s_st][c_st + 8]  = kreg1;
    *(bf16x8*)&Ks[s_st][c_st + 16] = kreg2;
    *(bf16x8*)&Ks[s_st][c_st + 24] = kreg3;
#pragma unroll
    for (int i = 0; i < 8; ++i) *(bf16x4*)&Vs[vd + i * 32][vc] = vreg[i];
    __syncthreads();

    if (kt + 1 < nkt) {   // T14: issue next tile's loads; latency hides under compute
      const int nb = colb + 32;
      const bf16_t* src = kgb + (size_t)(nb + s_st) * HD_ + c_st;
      kreg0 = *(const bf16x8*)(src);
      kreg1 = *(const bf16x8*)(src + 8);
      kreg2 = *(const bf16x8*)(src + 16);
      kreg3 = *(const bf16x8*)(src + 24);
#pragma unroll
      for (int i = 0; i < 8; ++i)
        vreg[i] = *(const bf16x4*)(vgb + (size_t)(vd + i * 32) * S_ + nb + vc);
    }

    if (colb <= q0 + 15) {   // wave active for this tile
      f32x4 s0 = {0.f, 0.f, 0.f, 0.f}, s1 = {0.f, 0.f, 0.f, 0.f};
#pragma unroll
      for (int c = 0; c < 8; ++c) {
        bf16x8 k0 = *(const bf16x8*)&Ks[lr][c * 32 + lg * 8];
        bf16x8 k1 = *(const bf16x8*)&Ks[16 + lr][c * 32 + lg * 8];
        s0 = __builtin_amdgcn_mfma_f32_16x16x32_bf16(qf[c], k0, s0, 0, 0, 0);
        s1 = __builtin_amdgcn_mfma_f32_16x16x32_bf16(qf[c], k1, s1, 0, 0, 0);
      }
      const int col0 = colb + lr, col1 = col0 + 16;
#pragma unroll
      for (int r = 0; r < 4; ++r) {
        const int row = q0 + rloc + r;
        const float pa = (col0 <= row) ? __expf(s0[r] * SCALE_ - mb[r]) : 0.0f;
        const float pb = (col1 <= row) ? __expf(s1[r] * SCALE_ - mb[r]) : 0.0f;
        l[r] += pa + pb;
        p_lds[w][rloc + r][lr]      = (bf16_t)pa;
        p_lds[w][rloc + r][lr + 16] = (bf16_t)pb;
      }
      bf16x8 pf = *(const bf16x8*)&p_lds[w][lr][lg * 8];   // P as A-fragment
#pragma unroll
      for (int df = 0; df < 16; ++df) {
        bf16x8 vf = *(const bf16x8*)&Vs[df * 16 + lr][lg * 8];
        oacc[df] = __builtin_amdgcn_mfma_f32_16x16x32_bf16(pf, vf, oacc[df], 0, 0, 0);
      }
      // coalesced bf16 p-tilde store
      {
        bf16x8 pv = *(const bf16x8*)&p_lds[w][prow][pcol];
        *(bf16x8*)(prow_g + (size_t)prow * S_ + colb + pcol) = pv;
      }
    }
  }
  // row sum l across lr lanes
#pragma unroll
  for (int r = 0; r < 4; ++r) {
    l[r] += __shfl_xor(l[r], 1);
    l[r] += __shfl_xor(l[r], 2);
    l[r] += __shfl_xor(l[r], 4);
    l[r] += __shfl_xor(l[r], 8);
  }
  float invl[4];
#pragma unroll
  for (int r = 0; r < 4; ++r) invl[r] = 1.0f / l[r];

  bf16_t* cp = ctx + ((size_t)b * S_ + q0) * DQ_ + h * HD_;
#pragma unroll
  for (int df = 0; df < 16; ++df)
#pragma unroll
    for (int r = 0; r < 4; ++r)
      cp[(size_t)(rloc + r) * DQ_ + df * 16 + lr] = (bf16_t)(oacc[df][r] * invl[r]);

  if (lr == 0) {
#pragma unroll
    for (int r = 0; r < 4; ++r) linv[(size_t)bh * S_ + q0 + rloc + r] = invl[r];
  }
}

// ---------------- weights finalize: read bf16 p-tilde, write normalized f32 + zeros ----------------
__global__ __launch_bounds__(256) void wscale_kernel(float* __restrict__ wbuf,
                                                     const bf16_t* __restrict__ pt,
                                                     const float* __restrict__ linv) {
  const int wv = threadIdx.x >> 6, lane = threadIdx.x & 63;
  const size_t rg = (size_t)blockIdx.x * 4 + wv;     // global row in (B*NH, S)
  const int row = (int)(rg & (S_ - 1));
  const float inv = linv[rg];
  const bf16_t* src = pt + rg * S_;
  float* base = wbuf + rg * S_;
#pragma unroll
  for (int i = 0; i < 8; ++i) {
    const int c0 = (i * 64 + lane) * 4;
    float4 v;
    if (c0 > row) {
      v = make_float4(0.f, 0.f, 0.f, 0.f);
    } else {
      bf16x4 bv = *(const bf16x4*)(src + c0);
      v.x = (c0 + 0 <= row) ? (float)bv[0] * inv : 0.f;
      v.y = (c0 + 1 <= row) ? (float)bv[1] * inv : 0.f;
      v.z = (c0 + 2 <= row) ? (float)bv[2] * inv : 0.f;
      v.w = (c0 + 3 <= row) ? (float)bv[3] * inv : 0.f;
    }
    *(float4*)(base + c0) = v;
  }
}

// ---------------- launch ----------------
extern "C" void kernel_launch(void* const* d_in, const int* in_sizes, int n_in,
                              void* d_out, int out_size, void* d_ws, size_t ws_size,
                              hipStream_t stream) {
  const float* hs   = (const float*)d_in[0];
  const float* cosb = (const float*)d_in[1];
  const float* sinb = (const float*)d_in[2];
  // d_in[3] attention_mask: recomputed causally in-kernel
  const float* Wq = (const float*)d_in[4];
  const float* Wk = (const float*)d_in[5];
  const float* Wv = (const float*)d_in[6];
  const float* Wo = (const float*)d_in[7];
  const float* qw = (const float*)d_in[8];
  const float* kw = (const float*)d_in[9];

  char* ws = (char*)d_ws;
  bf16_t* qb    = (bf16_t*)(ws + 0);            // 33,554,432  (B,NH,S,HD)
  bf16_t* kb    = (bf16_t*)(ws + 33554432);     // 16,777,216  (B,NKV,S,HD)
  bf16_t* vt    = (bf16_t*)(ws + 50331648);     // 16,777,216  (B,NKV,HD,S)
  bf16_t* ctx   = (bf16_t*)(ws + 67108864);     // 33,554,432  (B,S,NH*HD)
  float*  linv  = (float*)(ws + 100663296);     //    262,144
  float*  knorm = (float*)(ws + 100925440);     //    131,072
  float*  km    = (float*)(ws + 101056512);     //        128
  bf16_t* hsb   = (bf16_t*)(ws + 101056640);    // 29,360,128
  bf16_t* wqb   = (bf16_t*)(ws + 130416768);    // 29,360,128  (contiguous with wkb, wvb)
  bf16_t* wkb   = (bf16_t*)(ws + 159776896);    // 14,680,064
  bf16_t* wvb   = (bf16_t*)(ws + 174456960);    // 14,680,064
  bf16_t* wob   = (bf16_t*)(ws + 189137024);    // 29,360,128
  bf16_t* pt    = (bf16_t*)(ws + 218497152);    // 268,435,456 (B,NH,S,S) bf16
  float*  qnorm = (float*)(ws + 486932608);     //    262,144  -> total 487,194,752

  float* out      = (float*)d_out;
  float* attn_out = out;                            // (B,S,HID) f32
  float* weights  = out + (size_t)B_ * S_ * HID_;   // (B,NH,S,S) f32

  const int M = B_ * S_;  // 4096

  // 0) one-shot bf16 conversion of activations + weights
  cvt_kernel<<<14336, 256, 0, stream>>>(hs, hsb, (B_ * S_ * HID_) / 4);
  cvt_kernel<<<14336, 256, 0, stream>>>(Wq, wqb, (DQ_ * HID_) / 4);
  cvt_kernel<<<7168,  256, 0, stream>>>(Wk, wkb, (DKV_ * HID_) / 4);
  cvt_kernel<<<7168,  256, 0, stream>>>(Wv, wvb, (DKV_ * HID_) / 4);
  cvt_kernel<<<14336, 256, 0, stream>>>(Wo, wob, (HID_ * DQ_) / 4);

  // 1) merged Q|K|V projection: one 512-block launch (wqb|wkb|wvb contiguous, N=8192)
  gemm256<4><<<dim3((DQ_ + 2 * DKV_) / 256, M / 256), 512, 0, stream>>>(
      hsb, wqb, qb, kb, vt, M, DQ_ + 2 * DKV_, HID_);

  // 2) merged norm+rope (Q then K segments); emits qnorm + knorm
  normrope2_kernel<<<(B_ * S_ * (NH_ + NKV_)) / 4, 256, 0, stream>>>(
      qb, kb, qw, kw, cosb, sinb, qnorm, knorm);
  kmax_reduce_kernel<<<B_ * NKV_, 256, 0, stream>>>(knorm, km);

  // 3) single-pass attention (bf16 p-tilde into pt scratch), XCD-pinned 1-D grid
  attn1p_kernel<<<(S_ / 64) * (B_ * NH_), 256, 0, stream>>>(qb, kb, vt, qnorm, km, pt, linv, ctx);

  // 4) weights finalize: bf16 p-tilde -> normalized f32 + upper-triangle zeros
  wscale_kernel<<<(B_ * NH_ * S_) / 4, 256, 0, stream>>>(weights, pt, linv);

  // 5) output projection -> d_out (f32)
  gemm256<0><<<dim3(HID_ / 256, M / 256), 512, 0, stream>>>(
      ctx, wob, attn_out, nullptr, nullptr, M, HID_, DQ_);
}

// Round 19
// 863.866 us; speedup vs baseline: 1.0491x; 1.0491x over previous
//
#include <hip/hip_runtime.h>

// ---------------- problem constants ----------------
#define B_    2
#define S_    2048
#define HID_  3584
#define NH_   16
#define NKV_  8
#define HD_   256
#define DQ_   (NH_ * HD_)    // 4096
#define DKV_  (NKV_ * HD_)   // 2048

static constexpr float SCALE_ = 0.0625f;   // 256^-0.5

typedef __bf16 bf16_t;
typedef __bf16 bf16x8 __attribute__((ext_vector_type(8)));
typedef __bf16 bf16x4 __attribute__((ext_vector_type(4)));
typedef float  f32x4  __attribute__((ext_vector_type(4)));

// ---------------- f32 -> bf16 convert ----------------
__global__ __launch_bounds__(256) void cvt_kernel(const float* __restrict__ in,
                                                  bf16_t* __restrict__ out, int n4) {
  int i = blockIdx.x * 256 + threadIdx.x;
  if (i < n4) {
    float4 v = ((const float4*)in)[i];
    bf16x4 o;
    o[0] = (bf16_t)v.x; o[1] = (bf16_t)v.y; o[2] = (bf16_t)v.z; o[3] = (bf16_t)v.w;
    ((bf16x4*)out)[i] = o;
  }
}

// ---------------- async global->LDS, 16B per lane ----------------
__device__ inline void gload_lds16(const bf16_t* g, bf16_t* l) {
  __builtin_amdgcn_global_load_lds(
      (const __attribute__((address_space(1))) void*)g,
      (__attribute__((address_space(3))) void*)l, 16, 0, 0);
}

// ---------------- 256x256 8-wave pipelined GEMM: C[m][n] = sum_k A[m][k]*Bt[n][k] ----------------
// 512 thr = 2(M)x4(N) waves, each 128x64 C (acc[8][4]). BK=64, double-buffered 128KB LDS.
// 1-ahead prefetch, ALL 8 sites issued right after the barrier; single barrier per K-tile.
// Zigzag phase order (i0-3*j0-1 -> i0-3*j2-3 -> i4-7*j2-3 -> i4-7*j0-1) reuses fragments:
// 28 ds_read_b128/thread/tile instead of 32.
// Swizzle: source col unit ^= row&7 at staging; same XOR on ds_read (involution).
// MODE 0: OUT f32 row-major [M][N]          (o-proj -> d_out)
// MODE 1: OUT bf16 relayout (B, nh, S, HD)  (Q projection)
// MODE 3: combined KV: col<DKV -> K relayout into out; col>=DKV -> V transpose into out2
template<int MODE>
__global__ __launch_bounds__(512, 1) void gemm256(const bf16_t* __restrict__ A,
                                                  const bf16_t* __restrict__ Bt,
                                                  void* __restrict__ outv,
                                                  void* __restrict__ out2v,
                                                  int M, int N, int K, int nh) {
  __shared__ __align__(16) bf16_t As[2][256 * 64];   // 64 KB
  __shared__ __align__(16) bf16_t Bs[2][256 * 64];   // 64 KB
  const int t = threadIdx.x;
  const int lane = t & 63, wv = t >> 6;
  const int wr = wv >> 2, wc = wv & 3;
  const int lr = lane & 15, lg = lane >> 4;
  const size_t m0 = (size_t)blockIdx.y * 256, n0 = (size_t)blockIdx.x * 256;

  const int srow = wv * 8 + (lane >> 3);
  const int scol = ((lane & 7) ^ ((lane >> 3) & 7)) * 8;   // pre-swizzled source col
  const bf16_t* ga = A  + (m0 + srow) * (size_t)K + scol;
  const bf16_t* gb = Bt + (n0 + srow) * (size_t)K + scol;
  const int ldso = wv * 512;   // wave-uniform LDS offset (elems)

#define SITEA(rb, kc, pp) gload_lds16(ga + (size_t)(rb) * K + (kc), &As[pp][(rb) * 64 + ldso])
#define SITEB(rb, kc, pp) gload_lds16(gb + (size_t)(rb) * K + (kc), &Bs[pp][(rb) * 64 + ldso])

  const int NT = K >> 6;
  f32x4 acc[8][4] = {};
  bf16x8 af[4][2], b01[2][2], b23[2][2];

  const int swz0 = ((0 + lg) ^ (lr & 7)) * 8;
  const int swz1 = ((4 + lg) ^ (lr & 7)) * 8;
  const int aRB = (wr * 128 + lr) * 64;
  const int bRB = (wc * 64 + lr) * 64;

  SITEA(0, 0, 0); SITEA(64, 0, 0); SITEA(128, 0, 0); SITEA(192, 0, 0);
  SITEB(0, 0, 0); SITEB(64, 0, 0); SITEB(128, 0, 0); SITEB(192, 0, 0);

  for (int kt = 0; kt < NT; ++kt) {
    const int p = kt & 1, q = p ^ 1;
    __syncthreads();              // vmcnt drain: buf[p] staged & visible
    if (kt + 1 < NT) {            // issue ALL next-tile loads up front
      const int kn = (kt + 1) << 6;
      SITEA(0, kn, q); SITEA(64, kn, q); SITEA(128, kn, q); SITEA(192, kn, q);
      SITEB(0, kn, q); SITEB(64, kn, q); SITEB(128, kn, q); SITEB(192, kn, q);
    }

    // phase 0: read af(i0-3) + b01(j0-1); MFMA i0-3 x j0-1
#pragma unroll
    for (int i = 0; i < 4; ++i) {
      af[i][0] = *(const bf16x8*)&As[p][aRB + i * 1024 + swz0];
      af[i][1] = *(const bf16x8*)&As[p][aRB + i * 1024 + swz1];
    }
#pragma unroll
    for (int j = 0; j < 2; ++j) {
      b01[j][0] = *(const bf16x8*)&Bs[p][bRB + j * 1024 + swz0];
      b01[j][1] = *(const bf16x8*)&Bs[p][bRB + j * 1024 + swz1];
    }
#pragma unroll
    for (int i = 0; i < 4; ++i)
#pragma unroll
      for (int j = 0; j < 2; ++j) {
        acc[i][j] = __builtin_amdgcn_mfma_f32_16x16x32_bf16(af[i][0], b01[j][0], acc[i][j], 0, 0, 0);
        acc[i][j] = __builtin_amdgcn_mfma_f32_16x16x32_bf16(af[i][1], b01[j][1], acc[i][j], 0, 0, 0);
      }

    // phase 1: read b23(j2-3); MFMA i0-3 x j2-3 (af reused)
#pragma unroll
    for (int j = 0; j < 2; ++j) {
      b23[j][0] = *(const bf16x8*)&Bs[p][bRB + (j + 2) * 1024 + swz0];
      b23[j][1] = *(const bf16x8*)&Bs[p][bRB + (j + 2) * 1024 + swz1];
    }
#pragma unroll
    for (int i = 0; i < 4; ++i)
#pragma unroll
      for (int j = 0; j < 2; ++j) {
        acc[i][j + 2] = __builtin_amdgcn_mfma_f32_16x16x32_bf16(af[i][0], b23[j][0], acc[i][j + 2], 0, 0, 0);
        acc[i][j + 2] = __builtin_amdgcn_mfma_f32_16x16x32_bf16(af[i][1], b23[j][1], acc[i][j + 2], 0, 0, 0);
      }

    // phase 2: read af(i4-7); MFMA i4-7 x j2-3 (b23 reused)
#pragma unroll
    for (int i = 0; i < 4; ++i) {
      af[i][0] = *(const bf16x8*)&As[p][aRB + (i + 4) * 1024 + swz0];
      af[i][1] = *(const bf16x8*)&As[p][aRB + (i + 4) * 1024 + swz1];
    }
#pragma unroll
    for (int i = 0; i < 4; ++i)
#pragma unroll
      for (int j = 0; j < 2; ++j) {
        acc[i + 4][j + 2] = __builtin_amdgcn_mfma_f32_16x16x32_bf16(af[i][0], b23[j][0], acc[i + 4][j + 2], 0, 0, 0);
        acc[i + 4][j + 2] = __builtin_amdgcn_mfma_f32_16x16x32_bf16(af[i][1], b23[j][1], acc[i + 4][j + 2], 0, 0, 0);
      }

    // phase 3: re-read b01(j0-1); MFMA i4-7 x j0-1 (af reused)
#pragma unroll
    for (int j = 0; j < 2; ++j) {
      b01[j][0] = *(const bf16x8*)&Bs[p][bRB + j * 1024 + swz0];
      b01[j][1] = *(const bf16x8*)&Bs[p][bRB + j * 1024 + swz1];
    }
#pragma unroll
    for (int i = 0; i < 4; ++i)
#pragma unroll
      for (int j = 0; j < 2; ++j) {
        acc[i + 4][j] = __builtin_amdgcn_mfma_f32_16x16x32_bf16(af[i][0], b01[j][0], acc[i + 4][j], 0, 0, 0);
        acc[i + 4][j] = __builtin_amdgcn_mfma_f32_16x16x32_bf16(af[i][1], b01[j][1], acc[i + 4][j], 0, 0, 0);
      }
  }
#undef SITEA
#undef SITEB

#pragma unroll
  for (int i = 0; i < 8; ++i)
#pragma unroll
    for (int j = 0; j < 4; ++j) {
      const int row0 = (int)m0 + wr * 128 + i * 16 + lg * 4;
      const int col  = (int)n0 + wc * 64 + j * 16 + lr;
#pragma unroll
      for (int r = 0; r < 4; ++r) {
        const int row = row0 + r;
        if (MODE == 0) {
          ((float*)outv)[(size_t)row * N + col] = acc[i][j][r];
        } else {
          const bf16_t val = (bf16_t)acc[i][j][r];
          const int b = row >> 11, s = row & (S_ - 1);
          if (MODE == 1) {
            const int h = col >> 8, hd = col & (HD_ - 1);
            ((bf16_t*)outv)[((size_t)(b * nh + h) * S_ + s) * HD_ + hd] = val;
          } else {  // MODE 3: combined KV
            if (col < DKV_) {
              const int h = col >> 8, hd = col & (HD_ - 1);
              ((bf16_t*)outv)[((size_t)(b * NKV_ + h) * S_ + s) * HD_ + hd] = val;
            } else {
              const int c2 = col - DKV_;
              const int h = c2 >> 8, hd = c2 & (HD_ - 1);
              ((bf16_t*)out2v)[((size_t)(b * NKV_ + h) * HD_ + hd) * S_ + s] = val;
            }
          }
        }
      }
    }
}

// ---------------- fused RMSNorm + RoPE (in place), (b, s, h) block order ----------------
template<int LOGNH>
__global__ __launch_bounds__(256) void normrope_kernel(bf16_t* __restrict__ x,
                                                       const float* __restrict__ w,
                                                       const float* __restrict__ cosb,
                                                       const float* __restrict__ sinb,
                                                       float* __restrict__ rownorm) {
  const int gid  = blockIdx.x * 4 + (threadIdx.x >> 6);  // (b, s, h) order: h innermost
  const int lane = threadIdx.x & 63;
  const int nh = 1 << LOGNH;
  const int h  = gid & (nh - 1);
  const int bs = gid >> LOGNH;                 // b*S + s
  const int b  = bs >> 11, s = bs & (S_ - 1);
  const int rowi = (b * nh + h) * S_ + s;

  bf16_t* ptr = x + (size_t)rowi * HD_ + lane * 4;
  bf16x4 xv = *(const bf16x4*)ptr;
  float v0 = (float)xv[0], v1 = (float)xv[1], v2 = (float)xv[2], v3 = (float)xv[3];
  float ss = v0 * v0 + v1 * v1 + v2 * v2 + v3 * v3;
#pragma unroll
  for (int off = 1; off < 64; off <<= 1) ss += __shfl_xor(ss, off);
  float r = rsqrtf(ss * (1.0f / HD_) + 1e-6f);

  float4 wv = *(const float4*)(w + lane * 4);
  float x0 = v0 * r * (1.0f + wv.x);
  float x1 = v1 * r * (1.0f + wv.y);
  float x2 = v2 * r * (1.0f + wv.z);
  float x3 = v3 * r * (1.0f + wv.w);

  if (rownorm != nullptr) {   // row norm^2 after scale (RoPE preserves norm)
    float s2 = x0 * x0 + x1 * x1 + x2 * x2 + x3 * x3;
#pragma unroll
    for (int off = 1; off < 64; off <<= 1) s2 += __shfl_xor(s2, off);
    if (lane == 0) rownorm[rowi] = s2;
  }

  float p0 = __shfl_xor(x0, 32);
  float p1 = __shfl_xor(x1, 32);
  float p2 = __shfl_xor(x2, 32);
  float p3 = __shfl_xor(x3, 32);
  float sgn = (lane < 32) ? -1.0f : 1.0f;

  float4 c  = *(const float4*)(cosb + (size_t)bs * HD_ + lane * 4);
  float4 sn = *(const float4*)(sinb + (size_t)bs * HD_ + lane * 4);
  bf16x4 o;
  o[0] = (bf16_t)(x0 * c.x + sgn * p0 * sn.x);
  o[1] = (bf16_t)(x1 * c.y + sgn * p1 * sn.y);
  o[2] = (bf16_t)(x2 * c.z + sgn * p2 * sn.z);
  o[3] = (bf16_t)(x3 * c.w + sgn * p3 * sn.w);
  *(bf16x4*)ptr = o;
}

// ---------------- per-(b,kv-head) max of knorm ----------------
__global__ __launch_bounds__(256) void kmax_reduce_kernel(const float* __restrict__ knorm,
                                                          float* __restrict__ km) {
  __shared__ float red[4];
  const int t = threadIdx.x;
  const float* src = knorm + (size_t)blockIdx.x * S_;
  float m = 0.0f;
  for (int i = t; i < S_; i += 256) m = fmaxf(m, src[i]);
#pragma unroll
  for (int off = 1; off < 64; off <<= 1) m = fmaxf(m, __shfl_xor(m, off));
  if ((t & 63) == 0) red[t >> 6] = m;
  __syncthreads();
  if (t == 0) km[blockIdx.x] = fmaxf(fmaxf(red[0], red[1]), fmaxf(red[2], red[3]));
}

// ---------------- single-pass flash attention (XCD-pinned, LPT, T14 reg-prefetch) ----------------
__global__ __launch_bounds__(256) void attn1p_kernel(const bf16_t* __restrict__ qb,
                                                     const bf16_t* __restrict__ kb,
                                                     const bf16_t* __restrict__ vt,
                                                     const float* __restrict__ kmaxbuf,
                                                     bf16_t* __restrict__ pt,
                                                     float* __restrict__ linv,
                                                     bf16_t* __restrict__ ctx) {
  __shared__ __align__(16) bf16_t Ks[32][264];      // +8 pad
  __shared__ __align__(16) bf16_t Vs[256][36];      // d-major, +4 pad
  __shared__ __align__(16) bf16_t p_lds[4][16][36];
  __shared__ float qn_lds[4][16];

  const int t = threadIdx.x, w = t >> 6, lane = t & 63;
  const int lr = lane & 15, lg = lane >> 4, rloc = lg * 4;

  // XCD-pinned decode (wgid%8 = XCD round-robin); LPT: heavy q-buckets first
  const int wgid = blockIdx.x;
  const int g    = ((wgid >> 9) << 3) | (wgid & 7);   // (b*NKV + kvh) group, 0..15
  const int idx  = (wgid >> 3) & 63;
  const int b    = g >> 3, kvh = g & 7;
  const int h    = kvh * 2 + (idx >> 5);
  const int qbucket = 31 - (idx & 31);                // descending: longest first
  const int bh   = b * NH_ + h;
  const int q0b  = qbucket * 64;
  const int q0   = q0b + w * 16;

  const bf16_t* qptr = qb + ((size_t)bh * S_ + q0 + lr) * HD_ + lg * 8;
  bf16x8 qf[8];
#pragma unroll
  for (int c = 0; c < 8; ++c) qf[c] = *(const bf16x8*)(qptr + c * 32);

  float qn = 0.0f;
#pragma unroll
  for (int c = 0; c < 8; ++c)
#pragma unroll
    for (int e = 0; e < 8; ++e) { float v = (float)qf[c][e]; qn += v * v; }
  qn += __shfl_xor(qn, 16);
  qn += __shfl_xor(qn, 32);
  if (lg == 0) qn_lds[w][lr] = qn;
  __syncthreads();
  const float kmax2 = kmaxbuf[b * NKV_ + kvh];
  float mb[4];
#pragma unroll
  for (int r = 0; r < 4; ++r)
    mb[r] = SCALE_ * sqrtf(qn_lds[w][rloc + r] * kmax2) + 1.0f;  // >= any score, with margin

  float l[4] = {0.f, 0.f, 0.f, 0.f};
  f32x4 oacc[16] = {};
  const int nkt = (q0b + 64) >> 5;
  bf16_t* prow_g = pt + ((size_t)bh * S_ + q0) * S_;
  const bf16_t* kgb = kb + (size_t)(b * NKV_ + kvh) * S_ * HD_;
  const bf16_t* vgb = vt + (size_t)(b * NKV_ + kvh) * HD_ * S_;

  const int s_st = t >> 3, c_st = (t & 7) * 32;   // K staging: row s_st, 4x8 cols
  const int vd   = t >> 3, vc   = (t & 7) * 4;    // V staging: rows vd+32i, 4 cols
  const int prow = lane >> 2, pcol = (lane & 3) * 8;  // p-tilde store geometry

  // ---- prefetch tile 0 into registers ----
  bf16x8 kreg0, kreg1, kreg2, kreg3;
  bf16x4 vreg[8];
  {
    const bf16_t* src = kgb + (size_t)s_st * HD_ + c_st;
    kreg0 = *(const bf16x8*)(src);
    kreg1 = *(const bf16x8*)(src + 8);
    kreg2 = *(const bf16x8*)(src + 16);
    kreg3 = *(const bf16x8*)(src + 24);
#pragma unroll
    for (int i = 0; i < 8; ++i)
      vreg[i] = *(const bf16x4*)(vgb + (size_t)(vd + i * 32) * S_ + vc);
  }

  for (int kt = 0; kt < nkt; ++kt) {
    const int colb = kt * 32;
    __syncthreads();   // previous tile's LDS reads complete
    *(bf16x8*)&Ks[s_st][c_st]      = kreg0;
    *(bf16x8*)&Ks[s_st][c_st + 8]  = kreg1;
    *(bf16x8*)&Ks[s_st][c_st + 16] = kreg2;
    *(bf16x8*)&Ks[s_st][c_st + 24] = kreg3;
#pragma unroll
    for (int i = 0; i < 8; ++i) *(bf16x4*)&Vs[vd + i * 32][vc] = vreg[i];
    __syncthreads();

    if (kt + 1 < nkt) {   // T14: issue next tile's loads; latency hides under compute
      const int nb = colb + 32;
      const bf16_t* src = kgb + (size_t)(nb + s_st) * HD_ + c_st;
      kreg0 = *(const bf16x8*)(src);
      kreg1 = *(const bf16x8*)(src + 8);
      kreg2 = *(const bf16x8*)(src + 16);
      kreg3 = *(const bf16x8*)(src + 24);
#pragma unroll
      for (int i = 0; i < 8; ++i)
        vreg[i] = *(const bf16x4*)(vgb + (size_t)(vd + i * 32) * S_ + nb + vc);
    }

    if (colb <= q0 + 15) {   // wave active for this tile
      f32x4 s0 = {0.f, 0.f, 0.f, 0.f}, s1 = {0.f, 0.f, 0.f, 0.f};
#pragma unroll
      for (int c = 0; c < 8; ++c) {
        bf16x8 k0 = *(const bf16x8*)&Ks[lr][c * 32 + lg * 8];
        bf16x8 k1 = *(const bf16x8*)&Ks[16 + lr][c * 32 + lg * 8];
        s0 = __builtin_amdgcn_mfma_f32_16x16x32_bf16(qf[c], k0, s0, 0, 0, 0);
        s1 = __builtin_amdgcn_mfma_f32_16x16x32_bf16(qf[c], k1, s1, 0, 0, 0);
      }
      const int col0 = colb + lr, col1 = col0 + 16;
#pragma unroll
      for (int r = 0; r < 4; ++r) {
        const int row = q0 + rloc + r;
        const float pa = (col0 <= row) ? __expf(s0[r] * SCALE_ - mb[r]) : 0.0f;
        const float pb = (col1 <= row) ? __expf(s1[r] * SCALE_ - mb[r]) : 0.0f;
        l[r] += pa + pb;
        p_lds[w][rloc + r][lr]      = (bf16_t)pa;
        p_lds[w][rloc + r][lr + 16] = (bf16_t)pb;
      }
      bf16x8 pf = *(const bf16x8*)&p_lds[w][lr][lg * 8];   // P as A-fragment
#pragma unroll
      for (int df = 0; df < 16; ++df) {
        bf16x8 vf = *(const bf16x8*)&Vs[df * 16 + lr][lg * 8];
        oacc[df] = __builtin_amdgcn_mfma_f32_16x16x32_bf16(pf, vf, oacc[df], 0, 0, 0);
      }
      // coalesced bf16 p-tilde store
      {
        bf16x8 pv = *(const bf16x8*)&p_lds[w][prow][pcol];
        *(bf16x8*)(prow_g + (size_t)prow * S_ + colb + pcol) = pv;
      }
    }
  }
  // row sum l across lr lanes
#pragma unroll
  for (int r = 0; r < 4; ++r) {
    l[r] += __shfl_xor(l[r], 1);
    l[r] += __shfl_xor(l[r], 2);
    l[r] += __shfl_xor(l[r], 4);
    l[r] += __shfl_xor(l[r], 8);
  }
  float invl[4];
#pragma unroll
  for (int r = 0; r < 4; ++r) invl[r] = 1.0f / l[r];

  bf16_t* cp = ctx + ((size_t)b * S_ + q0) * DQ_ + h * HD_;
#pragma unroll
  for (int df = 0; df < 16; ++df)
#pragma unroll
    for (int r = 0; r < 4; ++r)
      cp[(size_t)(rloc + r) * DQ_ + df * 16 + lr] = (bf16_t)(oacc[df][r] * invl[r]);

  if (lr == 0) {
#pragma unroll
    for (int r = 0; r < 4; ++r) linv[(size_t)bh * S_ + q0 + rloc + r] = invl[r];
  }
}

// ---------------- weights finalize: read bf16 p-tilde, write normalized f32 + zeros ----------------
__global__ __launch_bounds__(256) void wscale_kernel(float* __restrict__ wbuf,
                                                     const bf16_t* __restrict__ pt,
                                                     const float* __restrict__ linv) {
  const int wv = threadIdx.x >> 6, lane = threadIdx.x & 63;
  const size_t rg = (size_t)blockIdx.x * 4 + wv;     // global row in (B*NH, S)
  const int row = (int)(rg & (S_ - 1));
  const float inv = linv[rg];
  const bf16_t* src = pt + rg * S_;
  float* base = wbuf + rg * S_;
#pragma unroll
  for (int i = 0; i < 8; ++i) {
    const int c0 = (i * 64 + lane) * 4;
    float4 v;
    if (c0 > row) {
      v = make_float4(0.f, 0.f, 0.f, 0.f);
    } else {
      bf16x4 bv = *(const bf16x4*)(src + c0);
      v.x = (c0 + 0 <= row) ? (float)bv[0] * inv : 0.f;
      v.y = (c0 + 1 <= row) ? (float)bv[1] * inv : 0.f;
      v.z = (c0 + 2 <= row) ? (float)bv[2] * inv : 0.f;
      v.w = (c0 + 3 <= row) ? (float)bv[3] * inv : 0.f;
    }
    *(float4*)(base + c0) = v;
  }
}

// ---------------- launch ----------------
extern "C" void kernel_launch(void* const* d_in, const int* in_sizes, int n_in,
                              void* d_out, int out_size, void* d_ws, size_t ws_size,
                              hipStream_t stream) {
  const float* hs   = (const float*)d_in[0];
  const float* cosb = (const float*)d_in[1];
  const float* sinb = (const float*)d_in[2];
  // d_in[3] attention_mask: recomputed causally in-kernel
  const float* Wq = (const float*)d_in[4];
  const float* Wk = (const float*)d_in[5];
  const float* Wv = (const float*)d_in[6];
  const float* Wo = (const float*)d_in[7];
  const float* qw = (const float*)d_in[8];
  const float* kw = (const float*)d_in[9];

  char* ws = (char*)d_ws;
  bf16_t* qb    = (bf16_t*)(ws + 0);            // 33,554,432  (B,NH,S,HD)
  bf16_t* kb    = (bf16_t*)(ws + 33554432);     // 16,777,216  (B,NKV,S,HD)
  bf16_t* vt    = (bf16_t*)(ws + 50331648);     // 16,777,216  (B,NKV,HD,S)
  bf16_t* ctx   = (bf16_t*)(ws + 67108864);     // 33,554,432  (B,S,NH*HD)
  float*  linv  = (float*)(ws + 100663296);     //    262,144
  float*  knorm = (float*)(ws + 100925440);     //    131,072
  float*  km    = (float*)(ws + 101056512);     //        128
  bf16_t* hsb   = (bf16_t*)(ws + 101056640);    // 29,360,128
  bf16_t* wqb   = (bf16_t*)(ws + 130416768);    // 29,360,128
  bf16_t* wkb   = (bf16_t*)(ws + 159776896);    // 14,680,064  (contiguous with wvb)
  bf16_t* wvb   = (bf16_t*)(ws + 174456960);    // 14,680,064
  bf16_t* wob   = (bf16_t*)(ws + 189137024);    // 29,360,128
  bf16_t* pt    = (bf16_t*)(ws + 218497152);    // 268,435,456 (B,NH,S,S) bf16 -> total 486,932,608

  float* out      = (float*)d_out;
  float* attn_out = out;                            // (B,S,HID) f32
  float* weights  = out + (size_t)B_ * S_ * HID_;   // (B,NH,S,S) f32

  const int M = B_ * S_;  // 4096

  // 0) one-shot bf16 conversion of activations + weights
  cvt_kernel<<<14336, 256, 0, stream>>>(hs, hsb, (B_ * S_ * HID_) / 4);
  cvt_kernel<<<14336, 256, 0, stream>>>(Wq, wqb, (DQ_ * HID_) / 4);
  cvt_kernel<<<7168,  256, 0, stream>>>(Wk, wkb, (DKV_ * HID_) / 4);
  cvt_kernel<<<7168,  256, 0, stream>>>(Wv, wvb, (DKV_ * HID_) / 4);
  cvt_kernel<<<14336, 256, 0, stream>>>(Wo, wob, (HID_ * DQ_) / 4);

  // 1) projections: 256x256 pipelined GEMMs (Q; fused K+V via contiguous wkb|wvb)
  gemm256<1><<<dim3(DQ_ / 256, M / 256), 512, 0, stream>>>(hsb, wqb, qb, nullptr, M, DQ_, HID_, NH_);
  gemm256<3><<<dim3((2 * DKV_) / 256, M / 256), 512, 0, stream>>>(hsb, wkb, kb, vt, M, 2 * DKV_, HID_, NKV_);

  // 2) norm + rope (in place); K pass also stores per-row |k|^2
  normrope_kernel<4><<<(B_ * S_ * NH_) / 4, 256, 0, stream>>>(qb, qw, cosb, sinb, nullptr);
  normrope_kernel<3><<<(B_ * S_ * NKV_) / 4, 256, 0, stream>>>(kb, kw, cosb, sinb, knorm);
  kmax_reduce_kernel<<<B_ * NKV_, 256, 0, stream>>>(knorm, km);

  // 3) single-pass attention (bf16 p-tilde into pt scratch), XCD-pinned 1-D grid
  attn1p_kernel<<<(S_ / 64) * (B_ * NH_), 256, 0, stream>>>(qb, kb, vt, km, pt, linv, ctx);

  // 4) weights finalize: bf16 p-tilde -> normalized f32 + upper-triangle zeros
  wscale_kernel<<<(B_ * NH_ * S_) / 4, 256, 0, stream>>>(weights, pt, linv);

  // 5) output projection -> d_out (f32)
  gemm256<0><<<dim3(HID_ / 256, M / 256), 512, 0, stream>>>(ctx, wob, attn_out, nullptr, M, HID_, DQ_, 0);
}

// Round 20
// 850.094 us; speedup vs baseline: 1.0661x; 1.0162x over previous
//
#include <hip/hip_runtime.h>

// ---------------- problem constants ----------------
#define B_    2
#define S_    2048
#define HID_  3584
#define NH_   16
#define NKV_  8
#define HD_   256
#define DQ_   (NH_ * HD_)    // 4096
#define DKV_  (NKV_ * HD_)   // 2048

static constexpr float SCALE_ = 0.0625f;   // 256^-0.5

typedef __bf16 bf16_t;
typedef __bf16 bf16x8 __attribute__((ext_vector_type(8)));
typedef __bf16 bf16x4 __attribute__((ext_vector_type(4)));
typedef float  f32x4  __attribute__((ext_vector_type(4)));

// ---------------- f32 -> bf16 convert ----------------
__global__ __launch_bounds__(256) void cvt_kernel(const float* __restrict__ in,
                                                  bf16_t* __restrict__ out, int n4) {
  int i = blockIdx.x * 256 + threadIdx.x;
  if (i < n4) {
    float4 v = ((const float4*)in)[i];
    bf16x4 o;
    o[0] = (bf16_t)v.x; o[1] = (bf16_t)v.y; o[2] = (bf16_t)v.z; o[3] = (bf16_t)v.w;
    ((bf16x4*)out)[i] = o;
  }
}

// ---------------- async global->LDS, 16B per lane ----------------
__device__ inline void gload_lds16(const bf16_t* g, bf16_t* l) {
  __builtin_amdgcn_global_load_lds(
      (const __attribute__((address_space(1))) void*)g,
      (__attribute__((address_space(3))) void*)l, 16, 0, 0);
}

// ---------------- 256x256 8-wave pipelined GEMM (R19 structure, unchanged) ----------------
// MODE 0: OUT f32 row-major [M][N]          (o-proj -> d_out)
// MODE 1: OUT bf16 relayout (B, nh, S, HD)  (Q projection)
// MODE 3: combined KV: col<DKV -> K relayout into out; col>=DKV -> V transpose into out2
template<int MODE>
__global__ __launch_bounds__(512, 1) void gemm256(const bf16_t* __restrict__ A,
                                                  const bf16_t* __restrict__ Bt,
                                                  void* __restrict__ outv,
                                                  void* __restrict__ out2v,
                                                  int M, int N, int K, int nh) {
  __shared__ __align__(16) bf16_t As[2][256 * 64];   // 64 KB
  __shared__ __align__(16) bf16_t Bs[2][256 * 64];   // 64 KB
  const int t = threadIdx.x;
  const int lane = t & 63, wv = t >> 6;
  const int wr = wv >> 2, wc = wv & 3;
  const int lr = lane & 15, lg = lane >> 4;
  const size_t m0 = (size_t)blockIdx.y * 256, n0 = (size_t)blockIdx.x * 256;

  const int srow = wv * 8 + (lane >> 3);
  const int scol = ((lane & 7) ^ ((lane >> 3) & 7)) * 8;   // pre-swizzled source col
  const bf16_t* ga = A  + (m0 + srow) * (size_t)K + scol;
  const bf16_t* gb = Bt + (n0 + srow) * (size_t)K + scol;
  const int ldso = wv * 512;   // wave-uniform LDS offset (elems)

#define SITEA(rb, kc, pp) gload_lds16(ga + (size_t)(rb) * K + (kc), &As[pp][(rb) * 64 + ldso])
#define SITEB(rb, kc, pp) gload_lds16(gb + (size_t)(rb) * K + (kc), &Bs[pp][(rb) * 64 + ldso])

  const int NT = K >> 6;
  f32x4 acc[8][4] = {};
  bf16x8 af[4][2], b01[2][2], b23[2][2];

  const int swz0 = ((0 + lg) ^ (lr & 7)) * 8;
  const int swz1 = ((4 + lg) ^ (lr & 7)) * 8;
  const int aRB = (wr * 128 + lr) * 64;
  const int bRB = (wc * 64 + lr) * 64;

  SITEA(0, 0, 0); SITEA(64, 0, 0); SITEA(128, 0, 0); SITEA(192, 0, 0);
  SITEB(0, 0, 0); SITEB(64, 0, 0); SITEB(128, 0, 0); SITEB(192, 0, 0);

  for (int kt = 0; kt < NT; ++kt) {
    const int p = kt & 1, q = p ^ 1;
    __syncthreads();              // vmcnt drain: buf[p] staged & visible
    if (kt + 1 < NT) {            // issue ALL next-tile loads up front
      const int kn = (kt + 1) << 6;
      SITEA(0, kn, q); SITEA(64, kn, q); SITEA(128, kn, q); SITEA(192, kn, q);
      SITEB(0, kn, q); SITEB(64, kn, q); SITEB(128, kn, q); SITEB(192, kn, q);
    }

    // phase 0: read af(i0-3) + b01(j0-1); MFMA i0-3 x j0-1
#pragma unroll
    for (int i = 0; i < 4; ++i) {
      af[i][0] = *(const bf16x8*)&As[p][aRB + i * 1024 + swz0];
      af[i][1] = *(const bf16x8*)&As[p][aRB + i * 1024 + swz1];
    }
#pragma unroll
    for (int j = 0; j < 2; ++j) {
      b01[j][0] = *(const bf16x8*)&Bs[p][bRB + j * 1024 + swz0];
      b01[j][1] = *(const bf16x8*)&Bs[p][bRB + j * 1024 + swz1];
    }
#pragma unroll
    for (int i = 0; i < 4; ++i)
#pragma unroll
      for (int j = 0; j < 2; ++j) {
        acc[i][j] = __builtin_amdgcn_mfma_f32_16x16x32_bf16(af[i][0], b01[j][0], acc[i][j], 0, 0, 0);
        acc[i][j] = __builtin_amdgcn_mfma_f32_16x16x32_bf16(af[i][1], b01[j][1], acc[i][j], 0, 0, 0);
      }

    // phase 1: read b23(j2-3); MFMA i0-3 x j2-3 (af reused)
#pragma unroll
    for (int j = 0; j < 2; ++j) {
      b23[j][0] = *(const bf16x8*)&Bs[p][bRB + (j + 2) * 1024 + swz0];
      b23[j][1] = *(const bf16x8*)&Bs[p][bRB + (j + 2) * 1024 + swz1];
    }
#pragma unroll
    for (int i = 0; i < 4; ++i)
#pragma unroll
      for (int j = 0; j < 2; ++j) {
        acc[i][j + 2] = __builtin_amdgcn_mfma_f32_16x16x32_bf16(af[i][0], b23[j][0], acc[i][j + 2], 0, 0, 0);
        acc[i][j + 2] = __builtin_amdgcn_mfma_f32_16x16x32_bf16(af[i][1], b23[j][1], acc[i][j + 2], 0, 0, 0);
      }

    // phase 2: read af(i4-7); MFMA i4-7 x j2-3 (b23 reused)
#pragma unroll
    for (int i = 0; i < 4; ++i) {
      af[i][0] = *(const bf16x8*)&As[p][aRB + (i + 4) * 1024 + swz0];
      af[i][1] = *(const bf16x8*)&As[p][aRB + (i + 4) * 1024 + swz1];
    }
#pragma unroll
    for (int i = 0; i < 4; ++i)
#pragma unroll
      for (int j = 0; j < 2; ++j) {
        acc[i + 4][j + 2] = __builtin_amdgcn_mfma_f32_16x16x32_bf16(af[i][0], b23[j][0], acc[i + 4][j + 2], 0, 0, 0);
        acc[i + 4][j + 2] = __builtin_amdgcn_mfma_f32_16x16x32_bf16(af[i][1], b23[j][1], acc[i + 4][j + 2], 0, 0, 0);
      }

    // phase 3: re-read b01(j0-1); MFMA i4-7 x j0-1 (af reused)
#pragma unroll
    for (int j = 0; j < 2; ++j) {
      b01[j][0] = *(const bf16x8*)&Bs[p][bRB + j * 1024 + swz0];
      b01[j][1] = *(const bf16x8*)&Bs[p][bRB + j * 1024 + swz1];
    }
#pragma unroll
    for (int i = 0; i < 4; ++i)
#pragma unroll
      for (int j = 0; j < 2; ++j) {
        acc[i + 4][j] = __builtin_amdgcn_mfma_f32_16x16x32_bf16(af[i][0], b01[j][0], acc[i + 4][j], 0, 0, 0);
        acc[i + 4][j] = __builtin_amdgcn_mfma_f32_16x16x32_bf16(af[i][1], b01[j][1], acc[i + 4][j], 0, 0, 0);
      }
  }
#undef SITEA
#undef SITEB

#pragma unroll
  for (int i = 0; i < 8; ++i)
#pragma unroll
    for (int j = 0; j < 4; ++j) {
      const int row0 = (int)m0 + wr * 128 + i * 16 + lg * 4;
      const int col  = (int)n0 + wc * 64 + j * 16 + lr;
#pragma unroll
      for (int r = 0; r < 4; ++r) {
        const int row = row0 + r;
        if (MODE == 0) {
          ((float*)outv)[(size_t)row * N + col] = acc[i][j][r];
        } else {
          const bf16_t val = (bf16_t)acc[i][j][r];
          const int b = row >> 11, s = row & (S_ - 1);
          if (MODE == 1) {
            const int h = col >> 8, hd = col & (HD_ - 1);
            ((bf16_t*)outv)[((size_t)(b * nh + h) * S_ + s) * HD_ + hd] = val;
          } else {  // MODE 3: combined KV
            if (col < DKV_) {
              const int h = col >> 8, hd = col & (HD_ - 1);
              ((bf16_t*)outv)[((size_t)(b * NKV_ + h) * S_ + s) * HD_ + hd] = val;
            } else {
              const int c2 = col - DKV_;
              const int h = c2 >> 8, hd = c2 & (HD_ - 1);
              ((bf16_t*)out2v)[((size_t)(b * NKV_ + h) * HD_ + hd) * S_ + s] = val;
            }
          }
        }
      }
    }
}

// ---------------- fused RMSNorm + RoPE (in place), (b, s, h) block order ----------------
template<int LOGNH>
__global__ __launch_bounds__(256) void normrope_kernel(bf16_t* __restrict__ x,
                                                       const float* __restrict__ w,
                                                       const float* __restrict__ cosb,
                                                       const float* __restrict__ sinb,
                                                       float* __restrict__ rownorm) {
  const int gid  = blockIdx.x * 4 + (threadIdx.x >> 6);  // (b, s, h) order: h innermost
  const int lane = threadIdx.x & 63;
  const int nh = 1 << LOGNH;
  const int h  = gid & (nh - 1);
  const int bs = gid >> LOGNH;                 // b*S + s
  const int b  = bs >> 11, s = bs & (S_ - 1);
  const int rowi = (b * nh + h) * S_ + s;

  bf16_t* ptr = x + (size_t)rowi * HD_ + lane * 4;
  bf16x4 xv = *(const bf16x4*)ptr;
  float v0 = (float)xv[0], v1 = (float)xv[1], v2 = (float)xv[2], v3 = (float)xv[3];
  float ss = v0 * v0 + v1 * v1 + v2 * v2 + v3 * v3;
#pragma unroll
  for (int off = 1; off < 64; off <<= 1) ss += __shfl_xor(ss, off);
  float r = rsqrtf(ss * (1.0f / HD_) + 1e-6f);

  float4 wv = *(const float4*)(w + lane * 4);
  float x0 = v0 * r * (1.0f + wv.x);
  float x1 = v1 * r * (1.0f + wv.y);
  float x2 = v2 * r * (1.0f + wv.z);
  float x3 = v3 * r * (1.0f + wv.w);

  if (rownorm != nullptr) {   // row norm^2 after scale (RoPE preserves norm)
    float s2 = x0 * x0 + x1 * x1 + x2 * x2 + x3 * x3;
#pragma unroll
    for (int off = 1; off < 64; off <<= 1) s2 += __shfl_xor(s2, off);
    if (lane == 0) rownorm[rowi] = s2;
  }

  float p0 = __shfl_xor(x0, 32);
  float p1 = __shfl_xor(x1, 32);
  float p2 = __shfl_xor(x2, 32);
  float p3 = __shfl_xor(x3, 32);
  float sgn = (lane < 32) ? -1.0f : 1.0f;

  float4 c  = *(const float4*)(cosb + (size_t)bs * HD_ + lane * 4);
  float4 sn = *(const float4*)(sinb + (size_t)bs * HD_ + lane * 4);
  bf16x4 o;
  o[0] = (bf16_t)(x0 * c.x + sgn * p0 * sn.x);
  o[1] = (bf16_t)(x1 * c.y + sgn * p1 * sn.y);
  o[2] = (bf16_t)(x2 * c.z + sgn * p2 * sn.z);
  o[3] = (bf16_t)(x3 * c.w + sgn * p3 * sn.w);
  *(bf16x4*)ptr = o;
}

// ---------------- per-(b,kv-head) max of knorm ----------------
__global__ __launch_bounds__(256) void kmax_reduce_kernel(const float* __restrict__ knorm,
                                                          float* __restrict__ km) {
  __shared__ float red[4];
  const int t = threadIdx.x;
  const float* src = knorm + (size_t)blockIdx.x * S_;
  float m = 0.0f;
  for (int i = t; i < S_; i += 256) m = fmaxf(m, src[i]);
#pragma unroll
  for (int off = 1; off < 64; off <<= 1) m = fmaxf(m, __shfl_xor(m, off));
  if ((t & 63) == 0) red[t >> 6] = m;
  __syncthreads();
  if (t == 0) km[blockIdx.x] = fmaxf(fmaxf(red[0], red[1]), fmaxf(red[2], red[3]));
}

// ---------------- single-pass flash attention, QBLK=128 (8 waves), XCD-pinned, LPT ----------------
// K/V staging shared by 8 waves (halved per-thread staging + halved L2 re-reads vs QBLK=64).
// Inner math identical to R19: bound-softmax, reg-prefetch (T14), bf16 p-tilde to pt.
__global__ __launch_bounds__(512) void attn1p_kernel(const bf16_t* __restrict__ qb,
                                                     const bf16_t* __restrict__ kb,
                                                     const bf16_t* __restrict__ vt,
                                                     const float* __restrict__ kmaxbuf,
                                                     bf16_t* __restrict__ pt,
                                                     float* __restrict__ linv,
                                                     bf16_t* __restrict__ ctx) {
  __shared__ __align__(16) bf16_t Ks[32][264];      // +8 pad (16.9 KB)
  __shared__ __align__(16) bf16_t Vs[256][36];      // d-major, +4 pad (18.4 KB)
  __shared__ __align__(16) bf16_t p_lds[8][16][36]; // 9.2 KB
  __shared__ float qn_lds[8][16];

  const int t = threadIdx.x, w = t >> 6, lane = t & 63;
  const int lr = lane & 15, lg = lane >> 4, rloc = lg * 4;

  // XCD-pinned decode for 512 blocks: g = ((wgid>>8)<<3)|(wgid&7) -> 16 groups x 32 blocks,
  // all 32 blocks of a (b,kvh) group share one XCD (wgid%8 round-robin). LPT descending.
  const int wgid = blockIdx.x;
  const int g    = ((wgid >> 8) << 3) | (wgid & 7);   // (b*NKV + kvh) group, 0..15
  const int idx  = (wgid >> 3) & 31;
  const int b    = g >> 3, kvh = g & 7;
  const int h    = kvh * 2 + (idx >> 4);              // GQA: 2 q-heads per group
  const int qbucket = 15 - (idx & 15);                // descending: longest first
  const int bh   = b * NH_ + h;
  const int q0b  = qbucket * 128;
  const int q0   = q0b + w * 16;                      // this wave's 16 q-rows

  const bf16_t* qptr = qb + ((size_t)bh * S_ + q0 + lr) * HD_ + lg * 8;
  bf16x8 qf[8];
#pragma unroll
  for (int c = 0; c < 8; ++c) qf[c] = *(const bf16x8*)(qptr + c * 32);

  float qn = 0.0f;
#pragma unroll
  for (int c = 0; c < 8; ++c)
#pragma unroll
    for (int e = 0; e < 8; ++e) { float v = (float)qf[c][e]; qn += v * v; }
  qn += __shfl_xor(qn, 16);
  qn += __shfl_xor(qn, 32);
  if (lg == 0) qn_lds[w][lr] = qn;
  __syncthreads();
  const float kmax2 = kmaxbuf[b * NKV_ + kvh];
  float mb[4];
#pragma unroll
  for (int r = 0; r < 4; ++r)
    mb[r] = SCALE_ * sqrtf(qn_lds[w][rloc + r] * kmax2) + 1.0f;  // >= any score, with margin

  float l[4] = {0.f, 0.f, 0.f, 0.f};
  f32x4 oacc[16] = {};
  const int nkt = (q0b + 128) >> 5;
  bf16_t* prow_g = pt + ((size_t)bh * S_ + q0) * S_;
  const bf16_t* kgb = kb + (size_t)(b * NKV_ + kvh) * S_ * HD_;
  const bf16_t* vgb = vt + (size_t)(b * NKV_ + kvh) * HD_ * S_;

  // 512-thread staging geometry
  const int s_st = t >> 4, c_st = (t & 15) * 16;  // K: row t>>4 (0-31), 2x bf16x8 cols
  const int vd   = t >> 3, vc   = (t & 7) * 4;    // V: rows vd+64i (i=0..3), 4 cols
  const int prow = lane >> 2, pcol = (lane & 3) * 8;  // p-tilde store geometry

  // ---- prefetch tile 0 into registers ----
  bf16x8 kreg0, kreg1;
  bf16x4 vreg[4];
  {
    const bf16_t* src = kgb + (size_t)s_st * HD_ + c_st;
    kreg0 = *(const bf16x8*)(src);
    kreg1 = *(const bf16x8*)(src + 8);
#pragma unroll
    for (int i = 0; i < 4; ++i)
      vreg[i] = *(const bf16x4*)(vgb + (size_t)(vd + i * 64) * S_ + vc);
  }

  for (int kt = 0; kt < nkt; ++kt) {
    const int colb = kt * 32;
    __syncthreads();   // previous tile's LDS reads complete
    *(bf16x8*)&Ks[s_st][c_st]     = kreg0;
    *(bf16x8*)&Ks[s_st][c_st + 8] = kreg1;
#pragma unroll
    for (int i = 0; i < 4; ++i) *(bf16x4*)&Vs[vd + i * 64][vc] = vreg[i];
    __syncthreads();

    if (kt + 1 < nkt) {   // T14: issue next tile's loads; latency hides under compute
      const int nb = colb + 32;
      const bf16_t* src = kgb + (size_t)(nb + s_st) * HD_ + c_st;
      kreg0 = *(const bf16x8*)(src);
      kreg1 = *(const bf16x8*)(src + 8);
#pragma unroll
      for (int i = 0; i < 4; ++i)
        vreg[i] = *(const bf16x4*)(vgb + (size_t)(vd + i * 64) * S_ + nb + vc);
    }

    if (colb <= q0 + 15) {   // wave active for this tile
      f32x4 s0 = {0.f, 0.f, 0.f, 0.f}, s1 = {0.f, 0.f, 0.f, 0.f};
#pragma unroll
      for (int c = 0; c < 8; ++c) {
        bf16x8 k0 = *(const bf16x8*)&Ks[lr][c * 32 + lg * 8];
        bf16x8 k1 = *(const bf16x8*)&Ks[16 + lr][c * 32 + lg * 8];
        s0 = __builtin_amdgcn_mfma_f32_16x16x32_bf16(qf[c], k0, s0, 0, 0, 0);
        s1 = __builtin_amdgcn_mfma_f32_16x16x32_bf16(qf[c], k1, s1, 0, 0, 0);
      }
      const int col0 = colb + lr, col1 = col0 + 16;
#pragma unroll
      for (int r = 0; r < 4; ++r) {
        const int row = q0 + rloc + r;
        const float pa = (col0 <= row) ? __expf(s0[r] * SCALE_ - mb[r]) : 0.0f;
        const float pb = (col1 <= row) ? __expf(s1[r] * SCALE_ - mb[r]) : 0.0f;
        l[r] += pa + pb;
        p_lds[w][rloc + r][lr]      = (bf16_t)pa;
        p_lds[w][rloc + r][lr + 16] = (bf16_t)pb;
      }
      bf16x8 pf = *(const bf16x8*)&p_lds[w][lr][lg * 8];   // P as A-fragment
#pragma unroll
      for (int df = 0; df < 16; ++df) {
        bf16x8 vf = *(const bf16x8*)&Vs[df * 16 + lr][lg * 8];
        oacc[df] = __builtin_amdgcn_mfma_f32_16x16x32_bf16(pf, vf, oacc[df], 0, 0, 0);
      }
      // coalesced bf16 p-tilde store
      {
        bf16x8 pv = *(const bf16x8*)&p_lds[w][prow][pcol];
        *(bf16x8*)(prow_g + (size_t)prow * S_ + colb + pcol) = pv;
      }
    }
  }
  // row sum l across lr lanes
#pragma unroll
  for (int r = 0; r < 4; ++r) {
    l[r] += __shfl_xor(l[r], 1);
    l[r] += __shfl_xor(l[r], 2);
    l[r] += __shfl_xor(l[r], 4);
    l[r] += __shfl_xor(l[r], 8);
  }
  float invl[4];
#pragma unroll
  for (int r = 0; r < 4; ++r) invl[r] = 1.0f / l[r];

  bf16_t* cp = ctx + ((size_t)b * S_ + q0) * DQ_ + h * HD_;
#pragma unroll
  for (int df = 0; df < 16; ++df)
#pragma unroll
    for (int r = 0; r < 4; ++r)
      cp[(size_t)(rloc + r) * DQ_ + df * 16 + lr] = (bf16_t)(oacc[df][r] * invl[r]);

  if (lr == 0) {
#pragma unroll
    for (int r = 0; r < 4; ++r) linv[(size_t)bh * S_ + q0 + rloc + r] = invl[r];
  }
}

// ---------------- weights finalize: read bf16 p-tilde, write normalized f32 + zeros ----------------
__global__ __launch_bounds__(256) void wscale_kernel(float* __restrict__ wbuf,
                                                     const bf16_t* __restrict__ pt,
                                                     const float* __restrict__ linv) {
  const int wv = threadIdx.x >> 6, lane = threadIdx.x & 63;
  const size_t rg = (size_t)blockIdx.x * 4 + wv;     // global row in (B*NH, S)
  const int row = (int)(rg & (S_ - 1));
  const float inv = linv[rg];
  const bf16_t* src = pt + rg * S_;
  float* base = wbuf + rg * S_;
#pragma unroll
  for (int i = 0; i < 8; ++i) {
    const int c0 = (i * 64 + lane) * 4;
    float4 v;
    if (c0 > row) {
      v = make_float4(0.f, 0.f, 0.f, 0.f);
    } else {
      bf16x4 bv = *(const bf16x4*)(src + c0);
      v.x = (c0 + 0 <= row) ? (float)bv[0] * inv : 0.f;
      v.y = (c0 + 1 <= row) ? (float)bv[1] * inv : 0.f;
      v.z = (c0 + 2 <= row) ? (float)bv[2] * inv : 0.f;
      v.w = (c0 + 3 <= row) ? (float)bv[3] * inv : 0.f;
    }
    *(float4*)(base + c0) = v;
  }
}

// ---------------- launch ----------------
extern "C" void kernel_launch(void* const* d_in, const int* in_sizes, int n_in,
                              void* d_out, int out_size, void* d_ws, size_t ws_size,
                              hipStream_t stream) {
  const float* hs   = (const float*)d_in[0];
  const float* cosb = (const float*)d_in[1];
  const float* sinb = (const float*)d_in[2];
  // d_in[3] attention_mask: recomputed causally in-kernel
  const float* Wq = (const float*)d_in[4];
  const float* Wk = (const float*)d_in[5];
  const float* Wv = (const float*)d_in[6];
  const float* Wo = (const float*)d_in[7];
  const float* qw = (const float*)d_in[8];
  const float* kw = (const float*)d_in[9];

  char* ws = (char*)d_ws;
  bf16_t* qb    = (bf16_t*)(ws + 0);            // 33,554,432  (B,NH,S,HD)
  bf16_t* kb    = (bf16_t*)(ws + 33554432);     // 16,777,216  (B,NKV,S,HD)
  bf16_t* vt    = (bf16_t*)(ws + 50331648);     // 16,777,216  (B,NKV,HD,S)
  bf16_t* ctx   = (bf16_t*)(ws + 67108864);     // 33,554,432  (B,S,NH*HD)
  float*  linv  = (float*)(ws + 100663296);     //    262,144
  float*  knorm = (float*)(ws + 100925440);     //    131,072
  float*  km    = (float*)(ws + 101056512);     //        128
  bf16_t* hsb   = (bf16_t*)(ws + 101056640);    // 29,360,128
  bf16_t* wqb   = (bf16_t*)(ws + 130416768);    // 29,360,128
  bf16_t* wkb   = (bf16_t*)(ws + 159776896);    // 14,680,064  (contiguous with wvb)
  bf16_t* wvb   = (bf16_t*)(ws + 174456960);    // 14,680,064
  bf16_t* wob   = (bf16_t*)(ws + 189137024);    // 29,360,128
  bf16_t* pt    = (bf16_t*)(ws + 218497152);    // 268,435,456 (B,NH,S,S) bf16 -> total 486,932,608

  float* out      = (float*)d_out;
  float* attn_out = out;                            // (B,S,HID) f32
  float* weights  = out + (size_t)B_ * S_ * HID_;   // (B,NH,S,S) f32

  const int M = B_ * S_;  // 4096

  // 0) one-shot bf16 conversion of activations + weights
  cvt_kernel<<<14336, 256, 0, stream>>>(hs, hsb, (B_ * S_ * HID_) / 4);
  cvt_kernel<<<14336, 256, 0, stream>>>(Wq, wqb, (DQ_ * HID_) / 4);
  cvt_kernel<<<7168,  256, 0, stream>>>(Wk, wkb, (DKV_ * HID_) / 4);
  cvt_kernel<<<7168,  256, 0, stream>>>(Wv, wvb, (DKV_ * HID_) / 4);
  cvt_kernel<<<14336, 256, 0, stream>>>(Wo, wob, (HID_ * DQ_) / 4);

  // 1) projections: 256x256 pipelined GEMMs (Q; fused K+V via contiguous wkb|wvb)
  gemm256<1><<<dim3(DQ_ / 256, M / 256), 512, 0, stream>>>(hsb, wqb, qb, nullptr, M, DQ_, HID_, NH_);
  gemm256<3><<<dim3((2 * DKV_) / 256, M / 256), 512, 0, stream>>>(hsb, wkb, kb, vt, M, 2 * DKV_, HID_, NKV_);

  // 2) norm + rope (in place); K pass also stores per-row |k|^2
  normrope_kernel<4><<<(B_ * S_ * NH_) / 4, 256, 0, stream>>>(qb, qw, cosb, sinb, nullptr);
  normrope_kernel<3><<<(B_ * S_ * NKV_) / 4, 256, 0, stream>>>(kb, kw, cosb, sinb, knorm);
  kmax_reduce_kernel<<<B_ * NKV_, 256, 0, stream>>>(knorm, km);

  // 3) single-pass attention QBLK=128 (bf16 p-tilde into pt), XCD-pinned 1-D grid
  attn1p_kernel<<<(S_ / 128) * (B_ * NH_), 512, 0, stream>>>(qb, kb, vt, km, pt, linv, ctx);

  // 4) weights finalize: bf16 p-tilde -> normalized f32 + upper-triangle zeros
  wscale_kernel<<<(B_ * NH_ * S_) / 4, 256, 0, stream>>>(weights, pt, linv);

  // 5) output projection -> d_out (f32)
  gemm256<0><<<dim3(HID_ / 256, M / 256), 512, 0, stream>>>(ctx, wob, attn_out, nullptr, M, HID_, DQ_, 0);
}

// Round 21
// 846.124 us; speedup vs baseline: 1.0711x; 1.0047x over previous
//
#include <hip/hip_runtime.h>

// ---------------- problem constants ----------------
#define B_    2
#define S_    2048
#define HID_  3584
#define NH_   16
#define NKV_  8
#define HD_   256
#define DQ_   (NH_ * HD_)    // 4096
#define DKV_  (NKV_ * HD_)   // 2048

static constexpr float SCALE_ = 0.0625f;   // 256^-0.5

typedef __bf16 bf16_t;
typedef __bf16 bf16x8 __attribute__((ext_vector_type(8)));
typedef __bf16 bf16x4 __attribute__((ext_vector_type(4)));
typedef float  f32x4  __attribute__((ext_vector_type(4)));

// ---------------- f32 -> bf16 convert ----------------
__global__ __launch_bounds__(256) void cvt_kernel(const float* __restrict__ in,
                                                  bf16_t* __restrict__ out, int n4) {
  int i = blockIdx.x * 256 + threadIdx.x;
  if (i < n4) {
    float4 v = ((const float4*)in)[i];
    bf16x4 o;
    o[0] = (bf16_t)v.x; o[1] = (bf16_t)v.y; o[2] = (bf16_t)v.z; o[3] = (bf16_t)v.w;
    ((bf16x4*)out)[i] = o;
  }
}

// ---------------- async global->LDS, 16B per lane ----------------
__device__ inline void gload_lds16(const bf16_t* g, bf16_t* l) {
  __builtin_amdgcn_global_load_lds(
      (const __attribute__((address_space(1))) void*)g,
      (__attribute__((address_space(3))) void*)l, 16, 0, 0);
}

// ---------------- 256x256 8-wave pipelined GEMM (R19 structure, unchanged) ----------------
// MODE 0: OUT f32 row-major [M][N]          (o-proj -> d_out)
// MODE 1: OUT bf16 relayout (B, nh, S, HD)  (Q projection)
// MODE 3: combined KV: col<DKV -> K relayout into out; col>=DKV -> V transpose into out2
template<int MODE>
__global__ __launch_bounds__(512, 1) void gemm256(const bf16_t* __restrict__ A,
                                                  const bf16_t* __restrict__ Bt,
                                                  void* __restrict__ outv,
                                                  void* __restrict__ out2v,
                                                  int M, int N, int K, int nh) {
  __shared__ __align__(16) bf16_t As[2][256 * 64];   // 64 KB
  __shared__ __align__(16) bf16_t Bs[2][256 * 64];   // 64 KB
  const int t = threadIdx.x;
  const int lane = t & 63, wv = t >> 6;
  const int wr = wv >> 2, wc = wv & 3;
  const int lr = lane & 15, lg = lane >> 4;
  const size_t m0 = (size_t)blockIdx.y * 256, n0 = (size_t)blockIdx.x * 256;

  const int srow = wv * 8 + (lane >> 3);
  const int scol = ((lane & 7) ^ ((lane >> 3) & 7)) * 8;   // pre-swizzled source col
  const bf16_t* ga = A  + (m0 + srow) * (size_t)K + scol;
  const bf16_t* gb = Bt + (n0 + srow) * (size_t)K + scol;
  const int ldso = wv * 512;   // wave-uniform LDS offset (elems)

#define SITEA(rb, kc, pp) gload_lds16(ga + (size_t)(rb) * K + (kc), &As[pp][(rb) * 64 + ldso])
#define SITEB(rb, kc, pp) gload_lds16(gb + (size_t)(rb) * K + (kc), &Bs[pp][(rb) * 64 + ldso])

  const int NT = K >> 6;
  f32x4 acc[8][4] = {};
  bf16x8 af[4][2], b01[2][2], b23[2][2];

  const int swz0 = ((0 + lg) ^ (lr & 7)) * 8;
  const int swz1 = ((4 + lg) ^ (lr & 7)) * 8;
  const int aRB = (wr * 128 + lr) * 64;
  const int bRB = (wc * 64 + lr) * 64;

  SITEA(0, 0, 0); SITEA(64, 0, 0); SITEA(128, 0, 0); SITEA(192, 0, 0);
  SITEB(0, 0, 0); SITEB(64, 0, 0); SITEB(128, 0, 0); SITEB(192, 0, 0);

  for (int kt = 0; kt < NT; ++kt) {
    const int p = kt & 1, q = p ^ 1;
    __syncthreads();              // vmcnt drain: buf[p] staged & visible
    if (kt + 1 < NT) {            // issue ALL next-tile loads up front
      const int kn = (kt + 1) << 6;
      SITEA(0, kn, q); SITEA(64, kn, q); SITEA(128, kn, q); SITEA(192, kn, q);
      SITEB(0, kn, q); SITEB(64, kn, q); SITEB(128, kn, q); SITEB(192, kn, q);
    }

    // phase 0: read af(i0-3) + b01(j0-1); MFMA i0-3 x j0-1
#pragma unroll
    for (int i = 0; i < 4; ++i) {
      af[i][0] = *(const bf16x8*)&As[p][aRB + i * 1024 + swz0];
      af[i][1] = *(const bf16x8*)&As[p][aRB + i * 1024 + swz1];
    }
#pragma unroll
    for (int j = 0; j < 2; ++j) {
      b01[j][0] = *(const bf16x8*)&Bs[p][bRB + j * 1024 + swz0];
      b01[j][1] = *(const bf16x8*)&Bs[p][bRB + j * 1024 + swz1];
    }
#pragma unroll
    for (int i = 0; i < 4; ++i)
#pragma unroll
      for (int j = 0; j < 2; ++j) {
        acc[i][j] = __builtin_amdgcn_mfma_f32_16x16x32_bf16(af[i][0], b01[j][0], acc[i][j], 0, 0, 0);
        acc[i][j] = __builtin_amdgcn_mfma_f32_16x16x32_bf16(af[i][1], b01[j][1], acc[i][j], 0, 0, 0);
      }

    // phase 1: read b23(j2-3); MFMA i0-3 x j2-3 (af reused)
#pragma unroll
    for (int j = 0; j < 2; ++j) {
      b23[j][0] = *(const bf16x8*)&Bs[p][bRB + (j + 2) * 1024 + swz0];
      b23[j][1] = *(const bf16x8*)&Bs[p][bRB + (j + 2) * 1024 + swz1];
    }
#pragma unroll
    for (int i = 0; i < 4; ++i)
#pragma unroll
      for (int j = 0; j < 2; ++j) {
        acc[i][j + 2] = __builtin_amdgcn_mfma_f32_16x16x32_bf16(af[i][0], b23[j][0], acc[i][j + 2], 0, 0, 0);
        acc[i][j + 2] = __builtin_amdgcn_mfma_f32_16x16x32_bf16(af[i][1], b23[j][1], acc[i][j + 2], 0, 0, 0);
      }

    // phase 2: read af(i4-7); MFMA i4-7 x j2-3 (b23 reused)
#pragma unroll
    for (int i = 0; i < 4; ++i) {
      af[i][0] = *(const bf16x8*)&As[p][aRB + (i + 4) * 1024 + swz0];
      af[i][1] = *(const bf16x8*)&As[p][aRB + (i + 4) * 1024 + swz1];
    }
#pragma unroll
    for (int i = 0; i < 4; ++i)
#pragma unroll
      for (int j = 0; j < 2; ++j) {
        acc[i + 4][j + 2] = __builtin_amdgcn_mfma_f32_16x16x32_bf16(af[i][0], b23[j][0], acc[i + 4][j + 2], 0, 0, 0);
        acc[i + 4][j + 2] = __builtin_amdgcn_mfma_f32_16x16x32_bf16(af[i][1], b23[j][1], acc[i + 4][j + 2], 0, 0, 0);
      }

    // phase 3: re-read b01(j0-1); MFMA i4-7 x j0-1 (af reused)
#pragma unroll
    for (int j = 0; j < 2; ++j) {
      b01[j][0] = *(const bf16x8*)&Bs[p][bRB + j * 1024 + swz0];
      b01[j][1] = *(const bf16x8*)&Bs[p][bRB + j * 1024 + swz1];
    }
#pragma unroll
    for (int i = 0; i < 4; ++i)
#pragma unroll
      for (int j = 0; j < 2; ++j) {
        acc[i + 4][j] = __builtin_amdgcn_mfma_f32_16x16x32_bf16(af[i][0], b01[j][0], acc[i + 4][j], 0, 0, 0);
        acc[i + 4][j] = __builtin_amdgcn_mfma_f32_16x16x32_bf16(af[i][1], b01[j][1], acc[i + 4][j], 0, 0, 0);
      }
  }
#undef SITEA
#undef SITEB

#pragma unroll
  for (int i = 0; i < 8; ++i)
#pragma unroll
    for (int j = 0; j < 4; ++j) {
      const int row0 = (int)m0 + wr * 128 + i * 16 + lg * 4;
      const int col  = (int)n0 + wc * 64 + j * 16 + lr;
#pragma unroll
      for (int r = 0; r < 4; ++r) {
        const int row = row0 + r;
        if (MODE == 0) {
          ((float*)outv)[(size_t)row * N + col] = acc[i][j][r];
        } else {
          const bf16_t val = (bf16_t)acc[i][j][r];
          const int b = row >> 11, s = row & (S_ - 1);
          if (MODE == 1) {
            const int h = col >> 8, hd = col & (HD_ - 1);
            ((bf16_t*)outv)[((size_t)(b * nh + h) * S_ + s) * HD_ + hd] = val;
          } else {  // MODE 3: combined KV
            if (col < DKV_) {
              const int h = col >> 8, hd = col & (HD_ - 1);
              ((bf16_t*)outv)[((size_t)(b * NKV_ + h) * S_ + s) * HD_ + hd] = val;
            } else {
              const int c2 = col - DKV_;
              const int h = c2 >> 8, hd = c2 & (HD_ - 1);
              ((bf16_t*)out2v)[((size_t)(b * NKV_ + h) * HD_ + hd) * S_ + s] = val;
            }
          }
        }
      }
    }
}

// ---------------- fused RMSNorm + RoPE (in place), (b, s, h) block order ----------------
template<int LOGNH>
__global__ __launch_bounds__(256) void normrope_kernel(bf16_t* __restrict__ x,
                                                       const float* __restrict__ w,
                                                       const float* __restrict__ cosb,
                                                       const float* __restrict__ sinb,
                                                       float* __restrict__ rownorm) {
  const int gid  = blockIdx.x * 4 + (threadIdx.x >> 6);  // (b, s, h) order: h innermost
  const int lane = threadIdx.x & 63;
  const int nh = 1 << LOGNH;
  const int h  = gid & (nh - 1);
  const int bs = gid >> LOGNH;                 // b*S + s
  const int b  = bs >> 11, s = bs & (S_ - 1);
  const int rowi = (b * nh + h) * S_ + s;

  bf16_t* ptr = x + (size_t)rowi * HD_ + lane * 4;
  bf16x4 xv = *(const bf16x4*)ptr;
  float v0 = (float)xv[0], v1 = (float)xv[1], v2 = (float)xv[2], v3 = (float)xv[3];
  float ss = v0 * v0 + v1 * v1 + v2 * v2 + v3 * v3;
#pragma unroll
  for (int off = 1; off < 64; off <<= 1) ss += __shfl_xor(ss, off);
  float r = rsqrtf(ss * (1.0f / HD_) + 1e-6f);

  float4 wv = *(const float4*)(w + lane * 4);
  float x0 = v0 * r * (1.0f + wv.x);
  float x1 = v1 * r * (1.0f + wv.y);
  float x2 = v2 * r * (1.0f + wv.z);
  float x3 = v3 * r * (1.0f + wv.w);

  if (rownorm != nullptr) {   // row norm^2 after scale (RoPE preserves norm)
    float s2 = x0 * x0 + x1 * x1 + x2 * x2 + x3 * x3;
#pragma unroll
    for (int off = 1; off < 64; off <<= 1) s2 += __shfl_xor(s2, off);
    if (lane == 0) rownorm[rowi] = s2;
  }

  float p0 = __shfl_xor(x0, 32);
  float p1 = __shfl_xor(x1, 32);
  float p2 = __shfl_xor(x2, 32);
  float p3 = __shfl_xor(x3, 32);
  float sgn = (lane < 32) ? -1.0f : 1.0f;

  float4 c  = *(const float4*)(cosb + (size_t)bs * HD_ + lane * 4);
  float4 sn = *(const float4*)(sinb + (size_t)bs * HD_ + lane * 4);
  bf16x4 o;
  o[0] = (bf16_t)(x0 * c.x + sgn * p0 * sn.x);
  o[1] = (bf16_t)(x1 * c.y + sgn * p1 * sn.y);
  o[2] = (bf16_t)(x2 * c.z + sgn * p2 * sn.z);
  o[3] = (bf16_t)(x3 * c.w + sgn * p3 * sn.w);
  *(bf16x4*)ptr = o;
}

// ---------------- per-(b,kv-head) max of knorm ----------------
__global__ __launch_bounds__(256) void kmax_reduce_kernel(const float* __restrict__ knorm,
                                                          float* __restrict__ km) {
  __shared__ float red[4];
  const int t = threadIdx.x;
  const float* src = knorm + (size_t)blockIdx.x * S_;
  float m = 0.0f;
  for (int i = t; i < S_; i += 256) m = fmaxf(m, src[i]);
#pragma unroll
  for (int off = 1; off < 64; off <<= 1) m = fmaxf(m, __shfl_xor(m, off));
  if ((t & 63) == 0) red[t >> 6] = m;
  __syncthreads();
  if (t == 0) km[blockIdx.x] = fmaxf(fmaxf(red[0], red[1]), fmaxf(red[2], red[3]));
}

// ---------------- single-pass flash attention, QBLK=128, double-buffered K/V LDS ----------------
// ONE barrier per kv-tile: writes to buf[cur] can only race tile i-2's readers of buf[cur],
// and the tile i-1 barrier (after every wave's i-2 compute) already orders them.
__global__ __launch_bounds__(512) void attn1p_kernel(const bf16_t* __restrict__ qb,
                                                     const bf16_t* __restrict__ kb,
                                                     const bf16_t* __restrict__ vt,
                                                     const float* __restrict__ kmaxbuf,
                                                     bf16_t* __restrict__ pt,
                                                     float* __restrict__ linv,
                                                     bf16_t* __restrict__ ctx) {
  __shared__ __align__(16) bf16_t Ks[2][32][264];   // +8 pad, double-buffered
  __shared__ __align__(16) bf16_t Vs[2][256][36];   // d-major, +4 pad, double-buffered
  __shared__ __align__(16) bf16_t p_lds[8][16][36];
  __shared__ float qn_lds[8][16];

  const int t = threadIdx.x, w = t >> 6, lane = t & 63;
  const int lr = lane & 15, lg = lane >> 4, rloc = lg * 4;

  // XCD-pinned decode (wgid%8 round-robin): 16 groups x 32 blocks; LPT descending
  const int wgid = blockIdx.x;
  const int g    = ((wgid >> 8) << 3) | (wgid & 7);   // (b*NKV + kvh) group, 0..15
  const int idx  = (wgid >> 3) & 31;
  const int b    = g >> 3, kvh = g & 7;
  const int h    = kvh * 2 + (idx >> 4);              // GQA: 2 q-heads per group
  const int qbucket = 15 - (idx & 15);                // descending: longest first
  const int bh   = b * NH_ + h;
  const int q0b  = qbucket * 128;
  const int q0   = q0b + w * 16;                      // this wave's 16 q-rows

  const bf16_t* qptr = qb + ((size_t)bh * S_ + q0 + lr) * HD_ + lg * 8;
  bf16x8 qf[8];
#pragma unroll
  for (int c = 0; c < 8; ++c) qf[c] = *(const bf16x8*)(qptr + c * 32);

  float qn = 0.0f;
#pragma unroll
  for (int c = 0; c < 8; ++c)
#pragma unroll
    for (int e = 0; e < 8; ++e) { float v = (float)qf[c][e]; qn += v * v; }
  qn += __shfl_xor(qn, 16);
  qn += __shfl_xor(qn, 32);
  if (lg == 0) qn_lds[w][lr] = qn;
  __syncthreads();
  const float kmax2 = kmaxbuf[b * NKV_ + kvh];
  float mb[4];
#pragma unroll
  for (int r = 0; r < 4; ++r)
    mb[r] = SCALE_ * sqrtf(qn_lds[w][rloc + r] * kmax2) + 1.0f;  // >= any score, with margin

  float l[4] = {0.f, 0.f, 0.f, 0.f};
  f32x4 oacc[16] = {};
  const int nkt = (q0b + 128) >> 5;
  bf16_t* prow_g = pt + ((size_t)bh * S_ + q0) * S_;
  const bf16_t* kgb = kb + (size_t)(b * NKV_ + kvh) * S_ * HD_;
  const bf16_t* vgb = vt + (size_t)(b * NKV_ + kvh) * HD_ * S_;

  // 512-thread staging geometry
  const int s_st = t >> 4, c_st = (t & 15) * 16;  // K: row t>>4 (0-31), 2x bf16x8 cols
  const int vd   = t >> 3, vc   = (t & 7) * 4;    // V: rows vd+64i (i=0..3), 4 cols
  const int prow = lane >> 2, pcol = (lane & 3) * 8;  // p-tilde store geometry

  // ---- prefetch tile 0 into registers ----
  bf16x8 kreg0, kreg1;
  bf16x4 vreg[4];
  {
    const bf16_t* src = kgb + (size_t)s_st * HD_ + c_st;
    kreg0 = *(const bf16x8*)(src);
    kreg1 = *(const bf16x8*)(src + 8);
#pragma unroll
    for (int i = 0; i < 4; ++i)
      vreg[i] = *(const bf16x4*)(vgb + (size_t)(vd + i * 64) * S_ + vc);
  }

  int cur = 0;
  for (int kt = 0; kt < nkt; ++kt) {
    const int colb = kt * 32;
    // write prefetched regs into buf[cur] (no pre-barrier: see race argument above)
    *(bf16x8*)&Ks[cur][s_st][c_st]     = kreg0;
    *(bf16x8*)&Ks[cur][s_st][c_st + 8] = kreg1;
#pragma unroll
    for (int i = 0; i < 4; ++i) *(bf16x4*)&Vs[cur][vd + i * 64][vc] = vreg[i];
    __syncthreads();   // single barrier: buf[cur] visible to all waves

    if (kt + 1 < nkt) {   // T14: issue next tile's loads; latency hides under compute
      const int nb = colb + 32;
      const bf16_t* src = kgb + (size_t)(nb + s_st) * HD_ + c_st;
      kreg0 = *(const bf16x8*)(src);
      kreg1 = *(const bf16x8*)(src + 8);
#pragma unroll
      for (int i = 0; i < 4; ++i)
        vreg[i] = *(const bf16x4*)(vgb + (size_t)(vd + i * 64) * S_ + nb + vc);
    }

    if (colb <= q0 + 15) {   // wave active for this tile
      f32x4 s0 = {0.f, 0.f, 0.f, 0.f}, s1 = {0.f, 0.f, 0.f, 0.f};
#pragma unroll
      for (int c = 0; c < 8; ++c) {
        bf16x8 k0 = *(const bf16x8*)&Ks[cur][lr][c * 32 + lg * 8];
        bf16x8 k1 = *(const bf16x8*)&Ks[cur][16 + lr][c * 32 + lg * 8];
        s0 = __builtin_amdgcn_mfma_f32_16x16x32_bf16(qf[c], k0, s0, 0, 0, 0);
        s1 = __builtin_amdgcn_mfma_f32_16x16x32_bf16(qf[c], k1, s1, 0, 0, 0);
      }
      const int col0 = colb + lr, col1 = col0 + 16;
#pragma unroll
      for (int r = 0; r < 4; ++r) {
        const int row = q0 + rloc + r;
        const float pa = (col0 <= row) ? __expf(s0[r] * SCALE_ - mb[r]) : 0.0f;
        const float pb = (col1 <= row) ? __expf(s1[r] * SCALE_ - mb[r]) : 0.0f;
        l[r] += pa + pb;
        p_lds[w][rloc + r][lr]      = (bf16_t)pa;
        p_lds[w][rloc + r][lr + 16] = (bf16_t)pb;
      }
      bf16x8 pf = *(const bf16x8*)&p_lds[w][lr][lg * 8];   // P as A-fragment
#pragma unroll
      for (int df = 0; df < 16; ++df) {
        bf16x8 vf = *(const bf16x8*)&Vs[cur][df * 16 + lr][lg * 8];
        oacc[df] = __builtin_amdgcn_mfma_f32_16x16x32_bf16(pf, vf, oacc[df], 0, 0, 0);
      }
      // coalesced bf16 p-tilde store
      {
        bf16x8 pv = *(const bf16x8*)&p_lds[w][prow][pcol];
        *(bf16x8*)(prow_g + (size_t)prow * S_ + colb + pcol) = pv;
      }
    }
    cur ^= 1;
  }
  // row sum l across lr lanes
#pragma unroll
  for (int r = 0; r < 4; ++r) {
    l[r] += __shfl_xor(l[r], 1);
    l[r] += __shfl_xor(l[r], 2);
    l[r] += __shfl_xor(l[r], 4);
    l[r] += __shfl_xor(l[r], 8);
  }
  float invl[4];
#pragma unroll
  for (int r = 0; r < 4; ++r) invl[r] = 1.0f / l[r];

  bf16_t* cp = ctx + ((size_t)b * S_ + q0) * DQ_ + h * HD_;
#pragma unroll
  for (int df = 0; df < 16; ++df)
#pragma unroll
    for (int r = 0; r < 4; ++r)
      cp[(size_t)(rloc + r) * DQ_ + df * 16 + lr] = (bf16_t)(oacc[df][r] * invl[r]);

  if (lr == 0) {
#pragma unroll
    for (int r = 0; r < 4; ++r) linv[(size_t)bh * S_ + q0 + rloc + r] = invl[r];
  }
}

// ---------------- weights finalize: read bf16 p-tilde, write normalized f32 + zeros ----------------
__global__ __launch_bounds__(256) void wscale_kernel(float* __restrict__ wbuf,
                                                     const bf16_t* __restrict__ pt,
                                                     const float* __restrict__ linv) {
  const int wv = threadIdx.x >> 6, lane = threadIdx.x & 63;
  const size_t rg = (size_t)blockIdx.x * 4 + wv;     // global row in (B*NH, S)
  const int row = (int)(rg & (S_ - 1));
  const float inv = linv[rg];
  const bf16_t* src = pt + rg * S_;
  float* base = wbuf + rg * S_;
#pragma unroll
  for (int i = 0; i < 8; ++i) {
    const int c0 = (i * 64 + lane) * 4;
    float4 v;
    if (c0 > row) {
      v = make_float4(0.f, 0.f, 0.f, 0.f);
    } else {
      bf16x4 bv = *(const bf16x4*)(src + c0);
      v.x = (c0 + 0 <= row) ? (float)bv[0] * inv : 0.f;
      v.y = (c0 + 1 <= row) ? (float)bv[1] * inv : 0.f;
      v.z = (c0 + 2 <= row) ? (float)bv[2] * inv : 0.f;
      v.w = (c0 + 3 <= row) ? (float)bv[3] * inv : 0.f;
    }
    *(float4*)(base + c0) = v;
  }
}

// ---------------- launch ----------------
extern "C" void kernel_launch(void* const* d_in, const int* in_sizes, int n_in,
                              void* d_out, int out_size, void* d_ws, size_t ws_size,
                              hipStream_t stream) {
  const float* hs   = (const float*)d_in[0];
  const float* cosb = (const float*)d_in[1];
  const float* sinb = (const float*)d_in[2];
  // d_in[3] attention_mask: recomputed causally in-kernel
  const float* Wq = (const float*)d_in[4];
  const float* Wk = (const float*)d_in[5];
  const float* Wv = (const float*)d_in[6];
  const float* Wo = (const float*)d_in[7];
  const float* qw = (const float*)d_in[8];
  const float* kw = (const float*)d_in[9];

  char* ws = (char*)d_ws;
  bf16_t* qb    = (bf16_t*)(ws + 0);            // 33,554,432  (B,NH,S,HD)
  bf16_t* kb    = (bf16_t*)(ws + 33554432);     // 16,777,216  (B,NKV,S,HD)
  bf16_t* vt    = (bf16_t*)(ws + 50331648);     // 16,777,216  (B,NKV,HD,S)
  bf16_t* ctx   = (bf16_t*)(ws + 67108864);     // 33,554,432  (B,S,NH*HD)
  float*  linv  = (float*)(ws + 100663296);     //    262,144
  float*  knorm = (float*)(ws + 100925440);     //    131,072
  float*  km    = (float*)(ws + 101056512);     //        128
  bf16_t* hsb   = (bf16_t*)(ws + 101056640);    // 29,360,128
  bf16_t* wqb   = (bf16_t*)(ws + 130416768);    // 29,360,128
  bf16_t* wkb   = (bf16_t*)(ws + 159776896);    // 14,680,064  (contiguous with wvb)
  bf16_t* wvb   = (bf16_t*)(ws + 174456960);    // 14,680,064
  bf16_t* wob   = (bf16_t*)(ws + 189137024);    // 29,360,128
  bf16_t* pt    = (bf16_t*)(ws + 218497152);    // 268,435,456 (B,NH,S,S) bf16 -> total 486,932,608

  float* out      = (float*)d_out;
  float* attn_out = out;                            // (B,S,HID) f32
  float* weights  = out + (size_t)B_ * S_ * HID_;   // (B,NH,S,S) f32

  const int M = B_ * S_;  // 4096

  // 0) one-shot bf16 conversion of activations + weights
  cvt_kernel<<<14336, 256, 0, stream>>>(hs, hsb, (B_ * S_ * HID_) / 4);
  cvt_kernel<<<14336, 256, 0, stream>>>(Wq, wqb, (DQ_ * HID_) / 4);
  cvt_kernel<<<7168,  256, 0, stream>>>(Wk, wkb, (DKV_ * HID_) / 4);
  cvt_kernel<<<7168,  256, 0, stream>>>(Wv, wvb, (DKV_ * HID_) / 4);
  cvt_kernel<<<14336, 256, 0, stream>>>(Wo, wob, (HID_ * DQ_) / 4);

  // 1) projections: 256x256 pipelined GEMMs (Q; fused K+V via contiguous wkb|wvb)
  gemm256<1><<<dim3(DQ_ / 256, M / 256), 512, 0, stream>>>(hsb, wqb, qb, nullptr, M, DQ_, HID_, NH_);
  gemm256<3><<<dim3((2 * DKV_) / 256, M / 256), 512, 0, stream>>>(hsb, wkb, kb, vt, M, 2 * DKV_, HID_, NKV_);

  // 2) norm + rope (in place); K pass also stores per-row |k|^2
  normrope_kernel<4><<<(B_ * S_ * NH_) / 4, 256, 0, stream>>>(qb, qw, cosb, sinb, nullptr);
  normrope_kernel<3><<<(B_ * S_ * NKV_) / 4, 256, 0, stream>>>(kb, kw, cosb, sinb, knorm);
  kmax_reduce_kernel<<<B_ * NKV_, 256, 0, stream>>>(knorm, km);

  // 3) single-pass attention QBLK=128, double-buffered K/V, XCD-pinned 1-D grid
  attn1p_kernel<<<(S_ / 128) * (B_ * NH_), 512, 0, stream>>>(qb, kb, vt, km, pt, linv, ctx);

  // 4) weights finalize: bf16 p-tilde -> normalized f32 + upper-triangle zeros
  wscale_kernel<<<(B_ * NH_ * S_) / 4, 256, 0, stream>>>(weights, pt, linv);

  // 5) output projection -> d_out (f32)
  gemm256<0><<<dim3(HID_ / 256, M / 256), 512, 0, stream>>>(ctx, wob, attn_out, nullptr, M, HID_, DQ_, 0);
}

// Round 22
// 833.385 us; speedup vs baseline: 1.0874x; 1.0153x over previous
//
#include <hip/hip_runtime.h>

// ---------------- problem constants ----------------
#define B_    2
#define S_    2048
#define HID_  3584
#define NH_   16
#define NKV_  8
#define HD_   256
#define DQ_   (NH_ * HD_)    // 4096
#define DKV_  (NKV_ * HD_)   // 2048

static constexpr float SCALE_ = 0.0625f;   // 256^-0.5

typedef __bf16 bf16_t;
typedef __bf16 bf16x8 __attribute__((ext_vector_type(8)));
typedef __bf16 bf16x4 __attribute__((ext_vector_type(4)));
typedef float  f32x4  __attribute__((ext_vector_type(4)));

// ---------------- merged f32 -> bf16 convert (hs|Wq|Wk|Wv|Wo -> contiguous dest) ----------------
__global__ __launch_bounds__(256) void cvt5_kernel(const float* __restrict__ s0,
                                                   const float* __restrict__ s1,
                                                   const float* __restrict__ s2,
                                                   const float* __restrict__ s3,
                                                   const float* __restrict__ s4,
                                                   bf16_t* __restrict__ out) {
  const size_t i = (size_t)blockIdx.x * 256 + threadIdx.x;   // f32x4 index
  // segment bounds in f32x4 units: hs 3670016 | Wq 3670016 | Wk 1835008 | Wv 1835008 | Wo 3670016
  const float* src; size_t off;
  if (i < 3670016)       { src = s0; off = i; }
  else if (i < 7340032)  { src = s1; off = i - 3670016; }
  else if (i < 9175040)  { src = s2; off = i - 7340032; }
  else if (i < 11010048) { src = s3; off = i - 9175040; }
  else                   { src = s4; off = i - 11010048; }
  float4 v = ((const float4*)src)[off];
  bf16x4 o;
  o[0] = (bf16_t)v.x; o[1] = (bf16_t)v.y; o[2] = (bf16_t)v.z; o[3] = (bf16_t)v.w;
  ((bf16x4*)out)[i] = o;
}

// ---------------- async global->LDS, 16B per lane ----------------
__device__ inline void gload_lds16(const bf16_t* g, bf16_t* l) {
  __builtin_amdgcn_global_load_lds(
      (const __attribute__((address_space(1))) void*)g,
      (__attribute__((address_space(3))) void*)l, 16, 0, 0);
}

// ---------------- 256x256 8-wave pipelined GEMM (R19 structure, unchanged) ----------------
// MODE 0: OUT f32 row-major [M][N]          (o-proj -> d_out)
// MODE 1: OUT bf16 relayout (B, nh, S, HD)  (Q projection)
// MODE 3: combined KV: col<DKV -> K relayout into out; col>=DKV -> V transpose into out2
template<int MODE>
__global__ __launch_bounds__(512, 1) void gemm256(const bf16_t* __restrict__ A,
                                                  const bf16_t* __restrict__ Bt,
                                                  void* __restrict__ outv,
                                                  void* __restrict__ out2v,
                                                  int M, int N, int K, int nh) {
  __shared__ __align__(16) bf16_t As[2][256 * 64];   // 64 KB
  __shared__ __align__(16) bf16_t Bs[2][256 * 64];   // 64 KB
  const int t = threadIdx.x;
  const int lane = t & 63, wv = t >> 6;
  const int wr = wv >> 2, wc = wv & 3;
  const int lr = lane & 15, lg = lane >> 4;
  const size_t m0 = (size_t)blockIdx.y * 256, n0 = (size_t)blockIdx.x * 256;

  const int srow = wv * 8 + (lane >> 3);
  const int scol = ((lane & 7) ^ ((lane >> 3) & 7)) * 8;   // pre-swizzled source col
  const bf16_t* ga = A  + (m0 + srow) * (size_t)K + scol;
  const bf16_t* gb = Bt + (n0 + srow) * (size_t)K + scol;
  const int ldso = wv * 512;   // wave-uniform LDS offset (elems)

#define SITEA(rb, kc, pp) gload_lds16(ga + (size_t)(rb) * K + (kc), &As[pp][(rb) * 64 + ldso])
#define SITEB(rb, kc, pp) gload_lds16(gb + (size_t)(rb) * K + (kc), &Bs[pp][(rb) * 64 + ldso])

  const int NT = K >> 6;
  f32x4 acc[8][4] = {};
  bf16x8 af[4][2], b01[2][2], b23[2][2];

  const int swz0 = ((0 + lg) ^ (lr & 7)) * 8;
  const int swz1 = ((4 + lg) ^ (lr & 7)) * 8;
  const int aRB = (wr * 128 + lr) * 64;
  const int bRB = (wc * 64 + lr) * 64;

  SITEA(0, 0, 0); SITEA(64, 0, 0); SITEA(128, 0, 0); SITEA(192, 0, 0);
  SITEB(0, 0, 0); SITEB(64, 0, 0); SITEB(128, 0, 0); SITEB(192, 0, 0);

  for (int kt = 0; kt < NT; ++kt) {
    const int p = kt & 1, q = p ^ 1;
    __syncthreads();              // vmcnt drain: buf[p] staged & visible
    if (kt + 1 < NT) {            // issue ALL next-tile loads up front
      const int kn = (kt + 1) << 6;
      SITEA(0, kn, q); SITEA(64, kn, q); SITEA(128, kn, q); SITEA(192, kn, q);
      SITEB(0, kn, q); SITEB(64, kn, q); SITEB(128, kn, q); SITEB(192, kn, q);
    }

    // phase 0: read af(i0-3) + b01(j0-1); MFMA i0-3 x j0-1
#pragma unroll
    for (int i = 0; i < 4; ++i) {
      af[i][0] = *(const bf16x8*)&As[p][aRB + i * 1024 + swz0];
      af[i][1] = *(const bf16x8*)&As[p][aRB + i * 1024 + swz1];
    }
#pragma unroll
    for (int j = 0; j < 2; ++j) {
      b01[j][0] = *(const bf16x8*)&Bs[p][bRB + j * 1024 + swz0];
      b01[j][1] = *(const bf16x8*)&Bs[p][bRB + j * 1024 + swz1];
    }
#pragma unroll
    for (int i = 0; i < 4; ++i)
#pragma unroll
      for (int j = 0; j < 2; ++j) {
        acc[i][j] = __builtin_amdgcn_mfma_f32_16x16x32_bf16(af[i][0], b01[j][0], acc[i][j], 0, 0, 0);
        acc[i][j] = __builtin_amdgcn_mfma_f32_16x16x32_bf16(af[i][1], b01[j][1], acc[i][j], 0, 0, 0);
      }

    // phase 1: read b23(j2-3); MFMA i0-3 x j2-3 (af reused)
#pragma unroll
    for (int j = 0; j < 2; ++j) {
      b23[j][0] = *(const bf16x8*)&Bs[p][bRB + (j + 2) * 1024 + swz0];
      b23[j][1] = *(const bf16x8*)&Bs[p][bRB + (j + 2) * 1024 + swz1];
    }
#pragma unroll
    for (int i = 0; i < 4; ++i)
#pragma unroll
      for (int j = 0; j < 2; ++j) {
        acc[i][j + 2] = __builtin_amdgcn_mfma_f32_16x16x32_bf16(af[i][0], b23[j][0], acc[i][j + 2], 0, 0, 0);
        acc[i][j + 2] = __builtin_amdgcn_mfma_f32_16x16x32_bf16(af[i][1], b23[j][1], acc[i][j + 2], 0, 0, 0);
      }

    // phase 2: read af(i4-7); MFMA i4-7 x j2-3 (b23 reused)
#pragma unroll
    for (int i = 0; i < 4; ++i) {
      af[i][0] = *(const bf16x8*)&As[p][aRB + (i + 4) * 1024 + swz0];
      af[i][1] = *(const bf16x8*)&As[p][aRB + (i + 4) * 1024 + swz1];
    }
#pragma unroll
    for (int i = 0; i < 4; ++i)
#pragma unroll
      for (int j = 0; j < 2; ++j) {
        acc[i + 4][j + 2] = __builtin_amdgcn_mfma_f32_16x16x32_bf16(af[i][0], b23[j][0], acc[i + 4][j + 2], 0, 0, 0);
        acc[i + 4][j + 2] = __builtin_amdgcn_mfma_f32_16x16x32_bf16(af[i][1], b23[j][1], acc[i + 4][j + 2], 0, 0, 0);
      }

    // phase 3: re-read b01(j0-1); MFMA i4-7 x j0-1 (af reused)
#pragma unroll
    for (int j = 0; j < 2; ++j) {
      b01[j][0] = *(const bf16x8*)&Bs[p][bRB + j * 1024 + swz0];
      b01[j][1] = *(const bf16x8*)&Bs[p][bRB + j * 1024 + swz1];
    }
#pragma unroll
    for (int i = 0; i < 4; ++i)
#pragma unroll
      for (int j = 0; j < 2; ++j) {
        acc[i + 4][j] = __builtin_amdgcn_mfma_f32_16x16x32_bf16(af[i][0], b01[j][0], acc[i + 4][j], 0, 0, 0);
        acc[i + 4][j] = __builtin_amdgcn_mfma_f32_16x16x32_bf16(af[i][1], b01[j][1], acc[i + 4][j], 0, 0, 0);
      }
  }
#undef SITEA
#undef SITEB

#pragma unroll
  for (int i = 0; i < 8; ++i)
#pragma unroll
    for (int j = 0; j < 4; ++j) {
      const int row0 = (int)m0 + wr * 128 + i * 16 + lg * 4;
      const int col  = (int)n0 + wc * 64 + j * 16 + lr;
#pragma unroll
      for (int r = 0; r < 4; ++r) {
        const int row = row0 + r;
        if (MODE == 0) {
          ((float*)outv)[(size_t)row * N + col] = acc[i][j][r];
        } else {
          const bf16_t val = (bf16_t)acc[i][j][r];
          const int b = row >> 11, s = row & (S_ - 1);
          if (MODE == 1) {
            const int h = col >> 8, hd = col & (HD_ - 1);
            ((bf16_t*)outv)[((size_t)(b * nh + h) * S_ + s) * HD_ + hd] = val;
          } else {  // MODE 3: combined KV
            if (col < DKV_) {
              const int h = col >> 8, hd = col & (HD_ - 1);
              ((bf16_t*)outv)[((size_t)(b * NKV_ + h) * S_ + s) * HD_ + hd] = val;
            } else {
              const int c2 = col - DKV_;
              const int h = c2 >> 8, hd = c2 & (HD_ - 1);
              ((bf16_t*)out2v)[((size_t)(b * NKV_ + h) * HD_ + hd) * S_ + s] = val;
            }
          }
        }
      }
    }
}

// ---------------- fused RMSNorm + RoPE (in place), (b, s, h) block order ----------------
template<int LOGNH>
__global__ __launch_bounds__(256) void normrope_kernel(bf16_t* __restrict__ x,
                                                       const float* __restrict__ w,
                                                       const float* __restrict__ cosb,
                                                       const float* __restrict__ sinb,
                                                       float* __restrict__ rownorm) {
  const int gid  = blockIdx.x * 4 + (threadIdx.x >> 6);  // (b, s, h) order: h innermost
  const int lane = threadIdx.x & 63;
  const int nh = 1 << LOGNH;
  const int h  = gid & (nh - 1);
  const int bs = gid >> LOGNH;                 // b*S + s
  const int b  = bs >> 11, s = bs & (S_ - 1);
  const int rowi = (b * nh + h) * S_ + s;

  bf16_t* ptr = x + (size_t)rowi * HD_ + lane * 4;
  bf16x4 xv = *(const bf16x4*)ptr;
  float v0 = (float)xv[0], v1 = (float)xv[1], v2 = (float)xv[2], v3 = (float)xv[3];
  float ss = v0 * v0 + v1 * v1 + v2 * v2 + v3 * v3;
#pragma unroll
  for (int off = 1; off < 64; off <<= 1) ss += __shfl_xor(ss, off);
  float r = rsqrtf(ss * (1.0f / HD_) + 1e-6f);

  float4 wv = *(const float4*)(w + lane * 4);
  float x0 = v0 * r * (1.0f + wv.x);
  float x1 = v1 * r * (1.0f + wv.y);
  float x2 = v2 * r * (1.0f + wv.z);
  float x3 = v3 * r * (1.0f + wv.w);

  if (rownorm != nullptr) {   // row norm^2 after scale (RoPE preserves norm)
    float s2 = x0 * x0 + x1 * x1 + x2 * x2 + x3 * x3;
#pragma unroll
    for (int off = 1; off < 64; off <<= 1) s2 += __shfl_xor(s2, off);
    if (lane == 0) rownorm[rowi] = s2;
  }

  float p0 = __shfl_xor(x0, 32);
  float p1 = __shfl_xor(x1, 32);
  float p2 = __shfl_xor(x2, 32);
  float p3 = __shfl_xor(x3, 32);
  float sgn = (lane < 32) ? -1.0f : 1.0f;

  float4 c  = *(const float4*)(cosb + (size_t)bs * HD_ + lane * 4);
  float4 sn = *(const float4*)(sinb + (size_t)bs * HD_ + lane * 4);
  bf16x4 o;
  o[0] = (bf16_t)(x0 * c.x + sgn * p0 * sn.x);
  o[1] = (bf16_t)(x1 * c.y + sgn * p1 * sn.y);
  o[2] = (bf16_t)(x2 * c.z + sgn * p2 * sn.z);
  o[3] = (bf16_t)(x3 * c.w + sgn * p3 * sn.w);
  *(bf16x4*)ptr = o;
}

// ---------------- per-(b,kv-head) max of knorm ----------------
__global__ __launch_bounds__(256) void kmax_reduce_kernel(const float* __restrict__ knorm,
                                                          float* __restrict__ km) {
  __shared__ float red[4];
  const int t = threadIdx.x;
  const float* src = knorm + (size_t)blockIdx.x * S_;
  float m = 0.0f;
  for (int i = t; i < S_; i += 256) m = fmaxf(m, src[i]);
#pragma unroll
  for (int off = 1; off < 64; off <<= 1) m = fmaxf(m, __shfl_xor(m, off));
  if ((t & 63) == 0) red[t >> 6] = m;
  __syncthreads();
  if (t == 0) km[blockIdx.x] = fmaxf(fmaxf(red[0], red[1]), fmaxf(red[2], red[3]));
}

// ---------------- single-pass flash attention, QBLK=128, double-buffered K/V LDS ----------------
// ONE barrier per kv-tile; T5 setprio around MFMA clusters (waves at diverse causal phases).
__global__ __launch_bounds__(512) void attn1p_kernel(const bf16_t* __restrict__ qb,
                                                     const bf16_t* __restrict__ kb,
                                                     const bf16_t* __restrict__ vt,
                                                     const float* __restrict__ kmaxbuf,
                                                     bf16_t* __restrict__ pt,
                                                     float* __restrict__ linv,
                                                     bf16_t* __restrict__ ctx) {
  __shared__ __align__(16) bf16_t Ks[2][32][264];   // +8 pad, double-buffered
  __shared__ __align__(16) bf16_t Vs[2][256][36];   // d-major, +4 pad, double-buffered
  __shared__ __align__(16) bf16_t p_lds[8][16][36];
  __shared__ float qn_lds[8][16];

  const int t = threadIdx.x, w = t >> 6, lane = t & 63;
  const int lr = lane & 15, lg = lane >> 4, rloc = lg * 4;

  // XCD-pinned decode (wgid%8 round-robin): 16 groups x 32 blocks; LPT descending
  const int wgid = blockIdx.x;
  const int g    = ((wgid >> 8) << 3) | (wgid & 7);   // (b*NKV + kvh) group, 0..15
  const int idx  = (wgid >> 3) & 31;
  const int b    = g >> 3, kvh = g & 7;
  const int h    = kvh * 2 + (idx >> 4);              // GQA: 2 q-heads per group
  const int qbucket = 15 - (idx & 15);                // descending: longest first
  const int bh   = b * NH_ + h;
  const int q0b  = qbucket * 128;
  const int q0   = q0b + w * 16;                      // this wave's 16 q-rows

  const bf16_t* qptr = qb + ((size_t)bh * S_ + q0 + lr) * HD_ + lg * 8;
  bf16x8 qf[8];
#pragma unroll
  for (int c = 0; c < 8; ++c) qf[c] = *(const bf16x8*)(qptr + c * 32);

  float qn = 0.0f;
#pragma unroll
  for (int c = 0; c < 8; ++c)
#pragma unroll
    for (int e = 0; e < 8; ++e) { float v = (float)qf[c][e]; qn += v * v; }
  qn += __shfl_xor(qn, 16);
  qn += __shfl_xor(qn, 32);
  if (lg == 0) qn_lds[w][lr] = qn;
  __syncthreads();
  const float kmax2 = kmaxbuf[b * NKV_ + kvh];
  float mb[4];
#pragma unroll
  for (int r = 0; r < 4; ++r)
    mb[r] = SCALE_ * sqrtf(qn_lds[w][rloc + r] * kmax2) + 1.0f;  // >= any score, with margin

  float l[4] = {0.f, 0.f, 0.f, 0.f};
  f32x4 oacc[16] = {};
  const int nkt = (q0b + 128) >> 5;
  bf16_t* prow_g = pt + ((size_t)bh * S_ + q0) * S_;
  const bf16_t* kgb = kb + (size_t)(b * NKV_ + kvh) * S_ * HD_;
  const bf16_t* vgb = vt + (size_t)(b * NKV_ + kvh) * HD_ * S_;

  // 512-thread staging geometry
  const int s_st = t >> 4, c_st = (t & 15) * 16;  // K: row t>>4 (0-31), 2x bf16x8 cols
  const int vd   = t >> 3, vc   = (t & 7) * 4;    // V: rows vd+64i (i=0..3), 4 cols
  const int prow = lane >> 2, pcol = (lane & 3) * 8;  // p-tilde store geometry

  // ---- prefetch tile 0 into registers ----
  bf16x8 kreg0, kreg1;
  bf16x4 vreg[4];
  {
    const bf16_t* src = kgb + (size_t)s_st * HD_ + c_st;
    kreg0 = *(const bf16x8*)(src);
    kreg1 = *(const bf16x8*)(src + 8);
#pragma unroll
    for (int i = 0; i < 4; ++i)
      vreg[i] = *(const bf16x4*)(vgb + (size_t)(vd + i * 64) * S_ + vc);
  }

  int cur = 0;
  for (int kt = 0; kt < nkt; ++kt) {
    const int colb = kt * 32;
    // write prefetched regs into buf[cur] (tile i-1 barrier orders vs tile i-2 readers)
    *(bf16x8*)&Ks[cur][s_st][c_st]     = kreg0;
    *(bf16x8*)&Ks[cur][s_st][c_st + 8] = kreg1;
#pragma unroll
    for (int i = 0; i < 4; ++i) *(bf16x4*)&Vs[cur][vd + i * 64][vc] = vreg[i];
    __syncthreads();   // single barrier: buf[cur] visible to all waves

    if (kt + 1 < nkt) {   // T14: issue next tile's loads; latency hides under compute
      const int nb = colb + 32;
      const bf16_t* src = kgb + (size_t)(nb + s_st) * HD_ + c_st;
      kreg0 = *(const bf16x8*)(src);
      kreg1 = *(const bf16x8*)(src + 8);
#pragma unroll
      for (int i = 0; i < 4; ++i)
        vreg[i] = *(const bf16x4*)(vgb + (size_t)(vd + i * 64) * S_ + nb + vc);
    }

    if (colb <= q0 + 15) {   // wave active for this tile
      f32x4 s0 = {0.f, 0.f, 0.f, 0.f}, s1 = {0.f, 0.f, 0.f, 0.f};
      __builtin_amdgcn_s_setprio(1);   // T5: favor MFMA-issuing wave
#pragma unroll
      for (int c = 0; c < 8; ++c) {
        bf16x8 k0 = *(const bf16x8*)&Ks[cur][lr][c * 32 + lg * 8];
        bf16x8 k1 = *(const bf16x8*)&Ks[cur][16 + lr][c * 32 + lg * 8];
        s0 = __builtin_amdgcn_mfma_f32_16x16x32_bf16(qf[c], k0, s0, 0, 0, 0);
        s1 = __builtin_amdgcn_mfma_f32_16x16x32_bf16(qf[c], k1, s1, 0, 0, 0);
      }
      __builtin_amdgcn_s_setprio(0);
      const int col0 = colb + lr, col1 = col0 + 16;
#pragma unroll
      for (int r = 0; r < 4; ++r) {
        const int row = q0 + rloc + r;
        const float pa = (col0 <= row) ? __expf(s0[r] * SCALE_ - mb[r]) : 0.0f;
        const float pb = (col1 <= row) ? __expf(s1[r] * SCALE_ - mb[r]) : 0.0f;
        l[r] += pa + pb;
        p_lds[w][rloc + r][lr]      = (bf16_t)pa;
        p_lds[w][rloc + r][lr + 16] = (bf16_t)pb;
      }
      bf16x8 pf = *(const bf16x8*)&p_lds[w][lr][lg * 8];   // P as A-fragment
      __builtin_amdgcn_s_setprio(1);
#pragma unroll
      for (int df = 0; df < 16; ++df) {
        bf16x8 vf = *(const bf16x8*)&Vs[cur][df * 16 + lr][lg * 8];
        oacc[df] = __builtin_amdgcn_mfma_f32_16x16x32_bf16(pf, vf, oacc[df], 0, 0, 0);
      }
      __builtin_amdgcn_s_setprio(0);
      // coalesced bf16 p-tilde store
      {
        bf16x8 pv = *(const bf16x8*)&p_lds[w][prow][pcol];
        *(bf16x8*)(prow_g + (size_t)prow * S_ + colb + pcol) = pv;
      }
    }
    cur ^= 1;
  }
  // row sum l across lr lanes
#pragma unroll
  for (int r = 0; r < 4; ++r) {
    l[r] += __shfl_xor(l[r], 1);
    l[r] += __shfl_xor(l[r], 2);
    l[r] += __shfl_xor(l[r], 4);
    l[r] += __shfl_xor(l[r], 8);
  }
  float invl[4];
#pragma unroll
  for (int r = 0; r < 4; ++r) invl[r] = 1.0f / l[r];

  bf16_t* cp = ctx + ((size_t)b * S_ + q0) * DQ_ + h * HD_;
#pragma unroll
  for (int df = 0; df < 16; ++df)
#pragma unroll
    for (int r = 0; r < 4; ++r)
      cp[(size_t)(rloc + r) * DQ_ + df * 16 + lr] = (bf16_t)(oacc[df][r] * invl[r]);

  if (lr == 0) {
#pragma unroll
    for (int r = 0; r < 4; ++r) linv[(size_t)bh * S_ + q0 + rloc + r] = invl[r];
  }
}

// ---------------- weights finalize: read bf16 p-tilde, write normalized f32 + zeros ----------------
__global__ __launch_bounds__(256) void wscale_kernel(float* __restrict__ wbuf,
                                                     const bf16_t* __restrict__ pt,
                                                     const float* __restrict__ linv) {
  const int wv = threadIdx.x >> 6, lane = threadIdx.x & 63;
  const size_t rg = (size_t)blockIdx.x * 4 + wv;     // global row in (B*NH, S)
  const int row = (int)(rg & (S_ - 1));
  const float inv = linv[rg];
  const bf16_t* src = pt + rg * S_;
  float* base = wbuf + rg * S_;
#pragma unroll
  for (int i = 0; i < 8; ++i) {
    const int c0 = (i * 64 + lane) * 4;
    float4 v;
    if (c0 > row) {
      v = make_float4(0.f, 0.f, 0.f, 0.f);
    } else {
      bf16x4 bv = *(const bf16x4*)(src + c0);
      v.x = (c0 + 0 <= row) ? (float)bv[0] * inv : 0.f;
      v.y = (c0 + 1 <= row) ? (float)bv[1] * inv : 0.f;
      v.z = (c0 + 2 <= row) ? (float)bv[2] * inv : 0.f;
      v.w = (c0 + 3 <= row) ? (float)bv[3] * inv : 0.f;
    }
    *(float4*)(base + c0) = v;
  }
}

// ---------------- launch ----------------
extern "C" void kernel_launch(void* const* d_in, const int* in_sizes, int n_in,
                              void* d_out, int out_size, void* d_ws, size_t ws_size,
                              hipStream_t stream) {
  const float* hs   = (const float*)d_in[0];
  const float* cosb = (const float*)d_in[1];
  const float* sinb = (const float*)d_in[2];
  // d_in[3] attention_mask: recomputed causally in-kernel
  const float* Wq = (const float*)d_in[4];
  const float* Wk = (const float*)d_in[5];
  const float* Wv = (const float*)d_in[6];
  const float* Wo = (const float*)d_in[7];
  const float* qw = (const float*)d_in[8];
  const float* kw = (const float*)d_in[9];

  char* ws = (char*)d_ws;
  bf16_t* qb    = (bf16_t*)(ws + 0);            // 33,554,432  (B,NH,S,HD)
  bf16_t* kb    = (bf16_t*)(ws + 33554432);     // 16,777,216  (B,NKV,S,HD)
  bf16_t* vt    = (bf16_t*)(ws + 50331648);     // 16,777,216  (B,NKV,HD,S)
  bf16_t* ctx   = (bf16_t*)(ws + 67108864);     // 33,554,432  (B,S,NH*HD)
  float*  linv  = (float*)(ws + 100663296);     //    262,144
  float*  knorm = (float*)(ws + 100925440);     //    131,072
  float*  km    = (float*)(ws + 101056512);     //        128
  bf16_t* hsb   = (bf16_t*)(ws + 101056640);    // 29,360,128  -+ contiguous cvt5 dest
  bf16_t* wqb   = (bf16_t*)(ws + 130416768);    // 29,360,128   |
  bf16_t* wkb   = (bf16_t*)(ws + 159776896);    // 14,680,064   |
  bf16_t* wvb   = (bf16_t*)(ws + 174456960);    // 14,680,064   |
  bf16_t* wob   = (bf16_t*)(ws + 189137024);    // 29,360,128  -+
  bf16_t* pt    = (bf16_t*)(ws + 218497152);    // 268,435,456 (B,NH,S,S) bf16 -> total 486,932,608

  float* out      = (float*)d_out;
  float* attn_out = out;                            // (B,S,HID) f32
  float* weights  = out + (size_t)B_ * S_ * HID_;   // (B,NH,S,S) f32

  const int M = B_ * S_;  // 4096

  // 0) merged one-shot bf16 conversion (hs|Wq|Wk|Wv|Wo -> hsb..wob contiguous)
  cvt5_kernel<<<57344, 256, 0, stream>>>(hs, Wq, Wk, Wv, Wo, hsb);

  // 1) projections: 256x256 pipelined GEMMs (Q; fused K+V via contiguous wkb|wvb)
  gemm256<1><<<dim3(DQ_ / 256, M / 256), 512, 0, stream>>>(hsb, wqb, qb, nullptr, M, DQ_, HID_, NH_);
  gemm256<3><<<dim3((2 * DKV_) / 256, M / 256), 512, 0, stream>>>(hsb, wkb, kb, vt, M, 2 * DKV_, HID_, NKV_);

  // 2) norm + rope (in place); K pass also stores per-row |k|^2
  normrope_kernel<4><<<(B_ * S_ * NH_) / 4, 256, 0, stream>>>(qb, qw, cosb, sinb, nullptr);
  normrope_kernel<3><<<(B_ * S_ * NKV_) / 4, 256, 0, stream>>>(kb, kw, cosb, sinb, knorm);
  kmax_reduce_kernel<<<B_ * NKV_, 256, 0, stream>>>(knorm, km);

  // 3) single-pass attention QBLK=128, double-buffered K/V, setprio, XCD-pinned 1-D grid
  attn1p_kernel<<<(S_ / 128) * (B_ * NH_), 512, 0, stream>>>(qb, kb, vt, km, pt, linv, ctx);

  // 4) weights finalize: bf16 p-tilde -> normalized f32 + upper-triangle zeros
  wscale_kernel<<<(B_ * NH_ * S_) / 4, 256, 0, stream>>>(weights, pt, linv);

  // 5) output projection -> d_out (f32)
  gemm256<0><<<dim3(HID_ / 256, M / 256), 512, 0, stream>>>(ctx, wob, attn_out, nullptr, M, HID_, DQ_, 0);
}